// Round 9
// baseline (2241.607 us; speedup 1.0000x reference)
//
#include <hip/hip_runtime.h>
#include <hip/hip_bf16.h>
#include <math.h>

#define B_SZ 16
#define T_LR 2560
#define BT (B_SZ * T_LR)     // 40960 tokens
#define DM 256               // d_model
#define DI 512               // d_inner
#define DS 16                // d_state
#define DTR 16               // dt_rank
#define CH 64                // scan chunks per sequence
#define CLEN (T_LR / CH)     // 40 steps per chunk

typedef __attribute__((ext_vector_type(8))) short bf16x8;
typedef __attribute__((ext_vector_type(4))) float f32x4;

__device__ __forceinline__ float silu_f(float x) {
    return x / (1.f + __expf(-x));
}
__device__ __forceinline__ unsigned short f2bf(float v) {
    __hip_bfloat16 h = __float2bfloat16(v);
    return *(unsigned short*)&h;
}
__device__ __forceinline__ float bf2f(unsigned short u) {
    union { unsigned int i; float f; } c;
    c.i = (unsigned int)u << 16;
    return c.f;
}
__device__ __forceinline__ int seqrev(int r) {
    int s = r / T_LR, t = r % T_LR;
    return s * T_LR + (T_LR - 1 - t);
}

// ---------------------------------------------------------------------------
// transpose (b,nch,T) f32 -> (b,T,nch) bf16
// ---------------------------------------------------------------------------
__global__ __launch_bounds__(256) void k_transp(const float* __restrict__ in,
                                                unsigned short* __restrict__ outb,
                                                int nch) {
    __shared__ float s[32][33];
    int b = blockIdx.z;
    int t0 = blockIdx.x * 32, c0 = blockIdx.y * 32;
    int tx = threadIdx.x & 31, ty = threadIdx.x >> 5;   // 32 x 8
    #pragma unroll
    for (int j = 0; j < 4; j++) {
        int c = c0 + ty + j * 8;
        s[ty + j * 8][tx] = in[((size_t)b * nch + c) * T_LR + t0 + tx];
    }
    __syncthreads();
    #pragma unroll
    for (int j = 0; j < 4; j++) {
        int t = t0 + ty + j * 8;
        outb[((size_t)b * T_LR + t) * nch + c0 + tx] = f2bf(s[tx][ty + j * 8]);
    }
}

// ---------------------------------------------------------------------------
// weight rearrange: in (N,K,3) f32 -> out [3][N][K] bf16
// ---------------------------------------------------------------------------
__global__ __launch_bounds__(256) void k_wrearr(const float* __restrict__ in,
                                                unsigned short* __restrict__ out,
                                                int N, int K) {
    int i = blockIdx.x * 256 + threadIdx.x;     // n*K + ci
    if (i >= N * K) return;
    int n = i / K, ci = i % K;
    #pragma unroll
    for (int k = 0; k < 3; k++)
        out[((size_t)k * N + n) * K + ci] = f2bf(in[((size_t)n * K + ci) * 3 + k]);
}

// ---------------------------------------------------------------------------
// fold BN into alpha/beta (256 ch): v = alpha*conv + beta
// ---------------------------------------------------------------------------
__global__ __launch_bounds__(256) void k_bnfold(const float* __restrict__ cb,
                                                const float* __restrict__ bng,
                                                const float* __restrict__ bnb,
                                                const float* __restrict__ bnm,
                                                const float* __restrict__ bnv,
                                                float* __restrict__ alpha,
                                                float* __restrict__ beta) {
    int c = threadIdx.x;
    float a = bng[c] * rsqrtf(bnv[c] + 1e-5f);
    alpha[c] = a;
    beta[c] = (cb[c] - bnm[c]) * a + bnb[c];
}

// ---------------------------------------------------------------------------
// combo weight: Wc[n][k] = sum_j dtW[n][j] * xW[j][k]   (512x512 bf16)
// ---------------------------------------------------------------------------
__global__ __launch_bounds__(256) void k_combo(const float* __restrict__ dtW,
                                               const float* __restrict__ xW,
                                               unsigned short* __restrict__ Wc) {
    int i = blockIdx.x * 256 + threadIdx.x;   // n*512 + k
    int n = i >> 9, k = i & 511;
    float v = 0.f;
    #pragma unroll
    for (int j = 0; j < 16; j++) v += dtW[n * 16 + j] * xW[j * 512 + k];
    Wc[i] = f2bf(v);
}

// ---------------------------------------------------------------------------
// f32 -> bf16 cast
// ---------------------------------------------------------------------------
__global__ __launch_bounds__(256) void k_cast(const float* __restrict__ in,
                                              unsigned short* __restrict__ out, int n) {
    int i = blockIdx.x * 256 + threadIdx.x;
    if (i < n) out[i] = f2bf(in[i]);
}

// ---------------------------------------------------------------------------
// implicit-GEMM k=3 "same" conv via MFMA (encoder/decoder convs).
// ---------------------------------------------------------------------------
__global__ __launch_bounds__(256) void k_conv3_bf(const unsigned short* __restrict__ A1, int K1,
                                                  const unsigned short* __restrict__ A2, int K2,
                                                  const unsigned short* __restrict__ W,
                                                  const float* __restrict__ alpha,
                                                  const float* __restrict__ beta,
                                                  float* __restrict__ outf,
                                                  unsigned short* __restrict__ outb,
                                                  int N, int dosilu, int pixsh) {
    int Kt = K1 + K2;
    __shared__ unsigned short As[130][40];
    __shared__ unsigned short Bs[3][128][40];
    int tid = threadIdx.x;
    int wave = tid >> 6, lane = tid & 63;
    int wm = (wave >> 1) * 64, wn = (wave & 1) * 64;
    int m0 = blockIdx.x * 128, n0 = blockIdx.y * 128;
    int b = m0 / T_LR, t0 = m0 % T_LR;
    int q = lane >> 4, ml = lane & 15;
    f32x4 acc[4][4] = {};
    for (int k0 = 0; k0 < Kt; k0 += 32) {
        __syncthreads();
        for (int i = tid; i < 520; i += 256) {
            int row = i >> 2, cq = i & 3;
            int t = t0 - 1 + row;
            uint4 v = make_uint4(0u, 0u, 0u, 0u);
            if (t >= 0 && t < T_LR) {
                int col = k0 + cq * 8;
                const unsigned short* src = (col < K1)
                    ? A1 + (size_t)(b * T_LR + t) * K1 + col
                    : A2 + (size_t)(b * T_LR + t) * K2 + (col - K1);
                v = *(const uint4*)src;
            }
            *(uint4*)&As[row][cq * 8] = v;
        }
        for (int i = tid; i < 1536; i += 256) {
            int tap = i >> 9;
            int r = (i >> 2) & 127;
            int cq = i & 3;
            *(uint4*)&Bs[tap][r][cq * 8] =
                *(const uint4*)(W + ((size_t)tap * N + n0 + r) * Kt + k0 + cq * 8);
        }
        __syncthreads();
        #pragma unroll
        for (int tap = 0; tap < 3; tap++) {
            bf16x8 bfr[4];
            #pragma unroll
            for (int ni = 0; ni < 4; ni++)
                bfr[ni] = *(const bf16x8*)&Bs[tap][wn + ni * 16 + ml][q * 8];
            #pragma unroll
            for (int mi = 0; mi < 4; mi++) {
                bf16x8 af = *(const bf16x8*)&As[wm + mi * 16 + ml + tap][q * 8];
                #pragma unroll
                for (int ni = 0; ni < 4; ni++)
                    acc[mi][ni] = __builtin_amdgcn_mfma_f32_16x16x32_bf16(af, bfr[ni], acc[mi][ni], 0, 0, 0);
            }
        }
    }
    #pragma unroll
    for (int mi = 0; mi < 4; mi++) {
        #pragma unroll
        for (int r = 0; r < 4; r++) {
            int mr = m0 + wm + mi * 16 + q * 4 + r;
            int t = mr - b * T_LR;
            #pragma unroll
            for (int ni = 0; ni < 4; ni++) {
                int col = n0 + wn + ni * 16 + ml;
                float a = alpha ? alpha[col] : 1.f;
                float v = acc[mi][ni][r] * a + beta[col];
                if (dosilu) v = silu_f(v);
                if (pixsh) {
                    int c2 = col >> 1, rr = col & 1;
                    outf[(((size_t)b * 64 + c2) * T_LR + t) * 2 + rr] = v;
                } else {
                    size_t o = (size_t)mr * N + col;
                    if (outf) outf[o] = v;
                    if (outb) outb[o] = f2bf(v);
                }
            }
        }
    }
}

// ---------------------------------------------------------------------------
// fused in_proj (xc half) + causal depthwise conv k=4 + silu -> xcs bf16.
// ---------------------------------------------------------------------------
__global__ __launch_bounds__(256) void k_inproj_conv(const unsigned short* __restrict__ xn,
                                                     const unsigned short* __restrict__ inW,
                                                     const float* __restrict__ cw,
                                                     const float* __restrict__ cb,
                                                     unsigned short* __restrict__ xcs,
                                                     int arev) {
    __shared__ unsigned short As[128][40];
    __shared__ unsigned short Bs[128][40];
    __shared__ unsigned short Ct[131][136];   // rows: internal t0-3 .. t0+127
    int tid = threadIdx.x;
    int wave = tid >> 6, lane = tid & 63;
    int wm = (wave >> 1) * 64, wn = (wave & 1) * 64;
    int m0 = blockIdx.x * 128, n0 = blockIdx.y * 128;
    int b = m0 / T_LR, t0 = m0 % T_LR;
    int sc = tid & 3, sr = tid >> 2;
    int ar0 = m0 + sr, ar1 = m0 + sr + 64;
    if (arev) { ar0 = seqrev(ar0); ar1 = seqrev(ar1); }
    const unsigned short* ap0 = xn + (size_t)ar0 * DM + sc * 8;
    const unsigned short* ap1 = xn + (size_t)ar1 * DM + sc * 8;
    const unsigned short* bp0 = inW + (size_t)(n0 + sr) * DM + sc * 8;
    const unsigned short* bp1 = inW + (size_t)(n0 + sr + 64) * DM + sc * 8;
    f32x4 acc[4][4] = {};
    int q = lane >> 4, ml = lane & 15;
    for (int k0 = 0; k0 < DM; k0 += 32) {
        uint4 a0 = *(const uint4*)(ap0 + k0);
        uint4 a1 = *(const uint4*)(ap1 + k0);
        uint4 b0 = *(const uint4*)(bp0 + k0);
        uint4 b1 = *(const uint4*)(bp1 + k0);
        __syncthreads();
        *(uint4*)&As[sr][sc * 8]      = a0;
        *(uint4*)&As[sr + 64][sc * 8] = a1;
        *(uint4*)&Bs[sr][sc * 8]      = b0;
        *(uint4*)&Bs[sr + 64][sc * 8] = b1;
        __syncthreads();
        bf16x8 af[4], bfr[4];
        #pragma unroll
        for (int mi = 0; mi < 4; mi++)
            af[mi] = *(const bf16x8*)&As[wm + mi * 16 + ml][q * 8];
        #pragma unroll
        for (int ni = 0; ni < 4; ni++)
            bfr[ni] = *(const bf16x8*)&Bs[wn + ni * 16 + ml][q * 8];
        #pragma unroll
        for (int mi = 0; mi < 4; mi++)
            #pragma unroll
            for (int ni = 0; ni < 4; ni++)
                acc[mi][ni] = __builtin_amdgcn_mfma_f32_16x16x32_bf16(af[mi], bfr[ni], acc[mi][ni], 0, 0, 0);
    }
    // main tile -> Ct rows 3..130
    #pragma unroll
    for (int mi = 0; mi < 4; mi++)
        #pragma unroll
        for (int r = 0; r < 4; r++)
            #pragma unroll
            for (int ni = 0; ni < 4; ni++)
                Ct[3 + wm + mi * 16 + q * 4 + r][wn + ni * 16 + ml] = f2bf(acc[mi][ni][r]);
    // halo rows 0..2 (internal t0-3..t0-1) via direct dot — 384 items on 256 threads
    for (int i = tid; i < 384; i += 256) {
        int hr = i >> 7, c = i & 127;
        int tr = t0 - 3 + hr;
        float v = 0.f;
        if (tr >= 0) {
            int src = b * T_LR + (arev ? (T_LR - 1 - tr) : tr);
            const unsigned short* xr = xn + (size_t)src * DM;
            const unsigned short* wr = inW + (size_t)(n0 + c) * DM;
            for (int k = 0; k < DM; k += 8) {
                uint4 xa = *(const uint4*)(xr + k);
                uint4 wa = *(const uint4*)(wr + k);
                const unsigned short* xs = (const unsigned short*)&xa;
                const unsigned short* wsp = (const unsigned short*)&wa;
                #pragma unroll
                for (int j = 0; j < 8; j++) v += bf2f(xs[j]) * bf2f(wsp[j]);
            }
        }
        Ct[hr][c] = f2bf(v);
    }
    __syncthreads();
    // causal conv k=4 + silu, write xcs bf16
    int col = tid & 127;
    int d = n0 + col;
    float w0 = cw[d * 4 + 0], w1 = cw[d * 4 + 1], w2 = cw[d * 4 + 2], w3 = cw[d * 4 + 3];
    float bi = cb[d];
    int rbase = tid >> 7;
    for (int j = 0; j < 64; j++) {
        int row = rbase + 2 * j;
        float v = bi + bf2f(Ct[row][col]) * w0 + bf2f(Ct[row + 1][col]) * w1
                     + bf2f(Ct[row + 2][col]) * w2 + bf2f(Ct[row + 3][col]) * w3;
        xcs[(size_t)(m0 + row) * DI + d] = f2bf(silu_f(v));
    }
}

// ---------------------------------------------------------------------------
// rmsnorm over last dim (256). One wave per token. fp32 and/or bf16 out.
// ---------------------------------------------------------------------------
__global__ __launch_bounds__(256) void k_rmsnorm(const float* __restrict__ in1,
                                                 const float* __restrict__ w,
                                                 float* __restrict__ out,
                                                 unsigned short* __restrict__ out_bf,
                                                 int ntok) {
    int tok = (blockIdx.x * 256 + threadIdx.x) >> 6;
    int lane = threadIdx.x & 63;
    if (tok >= ntok) return;
    float4 v = ((const float4*)(in1 + (size_t)tok * DM))[lane];
    float ss = v.x * v.x + v.y * v.y + v.z * v.z + v.w * v.w;
    #pragma unroll
    for (int off = 32; off > 0; off >>= 1) ss += __shfl_xor(ss, off);
    float sc = rsqrtf(ss * (1.f / 256.f) + 1e-6f);
    float4 wv = ((const float4*)w)[lane];
    float4 o;
    o.x = v.x * sc * wv.x; o.y = v.y * sc * wv.y;
    o.z = v.z * sc * wv.z; o.w = v.w * sc * wv.w;
    if (out) ((float4*)(out + (size_t)tok * DM))[lane] = o;
    if (out_bf) {
        ushort4 ob;
        ob.x = f2bf(o.x); ob.y = f2bf(o.y); ob.z = f2bf(o.z); ob.w = f2bf(o.w);
        ((ushort4*)(out_bf + (size_t)tok * DM))[lane] = ob;
    }
}

// ---------------------------------------------------------------------------
// bf16 MFMA GEMM, swiss-army epilogue (unchanged from r8).
// ---------------------------------------------------------------------------
__global__ __launch_bounds__(256) void k_gemm_bf(const unsigned short* __restrict__ A, int lda,
                                                 const unsigned short* __restrict__ Bw,
                                                 float* Cf, unsigned short* Cb, int ldc,
                                                 const float* __restrict__ res,
                                                 const float* __restrict__ bias,
                                                 const unsigned short* __restrict__ gate,
                                                 int K, int Nout, int act,
                                                 int arev, int crev, int accum) {
    __shared__ unsigned short As[128][40];
    __shared__ unsigned short Bs[128][40];
    int tid = threadIdx.x;
    int wave = tid >> 6, lane = tid & 63;
    int wm = (wave >> 1) * 64, wn = (wave & 1) * 64;
    int m0 = blockIdx.x * 128, n0 = blockIdx.y * 128;
    int sc = tid & 3, sr = tid >> 2;
    int ar0 = m0 + sr, ar1 = m0 + sr + 64;
    if (arev) { ar0 = seqrev(ar0); ar1 = seqrev(ar1); }
    const unsigned short* ap0 = A + (size_t)ar0 * lda + sc * 8;
    const unsigned short* ap1 = A + (size_t)ar1 * lda + sc * 8;
    bool bv0 = (n0 + sr) < Nout;
    bool bv1 = (n0 + sr + 64) < Nout;
    const unsigned short* bp0 = Bw + (size_t)(n0 + sr) * K + sc * 8;
    const unsigned short* bp1 = Bw + (size_t)(n0 + sr + 64) * K + sc * 8;
    f32x4 acc[4][4] = {};
    int q = lane >> 4, ml = lane & 15;
    for (int k0 = 0; k0 < K; k0 += 32) {
        uint4 a0 = *(const uint4*)(ap0 + k0);
        uint4 a1 = *(const uint4*)(ap1 + k0);
        uint4 b0 = make_uint4(0u, 0u, 0u, 0u), b1 = make_uint4(0u, 0u, 0u, 0u);
        if (bv0) b0 = *(const uint4*)(bp0 + k0);
        if (bv1) b1 = *(const uint4*)(bp1 + k0);
        __syncthreads();
        *(uint4*)&As[sr][sc * 8]      = a0;
        *(uint4*)&As[sr + 64][sc * 8] = a1;
        *(uint4*)&Bs[sr][sc * 8]      = b0;
        *(uint4*)&Bs[sr + 64][sc * 8] = b1;
        __syncthreads();
        bf16x8 af[4], bfr[4];
        #pragma unroll
        for (int mi = 0; mi < 4; mi++)
            af[mi] = *(const bf16x8*)&As[wm + mi * 16 + ml][q * 8];
        #pragma unroll
        for (int ni = 0; ni < 4; ni++)
            bfr[ni] = *(const bf16x8*)&Bs[wn + ni * 16 + ml][q * 8];
        #pragma unroll
        for (int mi = 0; mi < 4; mi++)
            #pragma unroll
            for (int ni = 0; ni < 4; ni++)
                acc[mi][ni] = __builtin_amdgcn_mfma_f32_16x16x32_bf16(af[mi], bfr[ni], acc[mi][ni], 0, 0, 0);
    }
    #pragma unroll
    for (int mi = 0; mi < 4; mi++) {
        #pragma unroll
        for (int r = 0; r < 4; r++) {
            int mr = m0 + wm + mi * 16 + q * 4 + r;
            int orow = crev ? seqrev(mr) : mr;
            #pragma unroll
            for (int ni = 0; ni < 4; ni++) {
                int col = n0 + wn + ni * 16 + ml;
                if (col < Nout) {
                    float v = acc[mi][ni][r];
                    if (bias) v += bias[col];
                    if (act == 2) v = (v > 20.f) ? v : log1pf(__expf(v));
                    if (gate) v = silu_f(v) * bf2f(gate[(size_t)mr * ldc + col]);
                    if (res) v += res[(size_t)orow * ldc + col];
                    if (accum) v += Cf[(size_t)orow * ldc + col];
                    if (Cf) Cf[(size_t)orow * ldc + col] = v;
                    if (Cb) Cb[(size_t)orow * ldc + col] = f2bf(v);
                }
            }
        }
    }
}

// ---------------------------------------------------------------------------
// merged dt+db GEMM: A = xcs (M,512) bf16; W = WcAll (544,512) bf16.
// cols 0..511: dt = softplus(v + dtb) -> bf16 (ld DI)
// cols 512..543: db = v -> fp32 (ld 32)
// ---------------------------------------------------------------------------
__global__ __launch_bounds__(256) void k_gemm_dtdb(const unsigned short* __restrict__ A,
                                                   const unsigned short* __restrict__ W,
                                                   unsigned short* __restrict__ dt,
                                                   float* __restrict__ db,
                                                   const float* __restrict__ dtb) {
    __shared__ unsigned short As[128][40];
    __shared__ unsigned short Bs[128][40];
    int tid = threadIdx.x;
    int wave = tid >> 6, lane = tid & 63;
    int wm = (wave >> 1) * 64, wn = (wave & 1) * 64;
    int m0 = blockIdx.x * 128, n0 = blockIdx.y * 128;
    int sc = tid & 3, sr = tid >> 2;
    const unsigned short* ap0 = A + (size_t)(m0 + sr) * DI + sc * 8;
    const unsigned short* ap1 = A + (size_t)(m0 + sr + 64) * DI + sc * 8;
    bool bv0 = (n0 + sr) < 544;
    bool bv1 = (n0 + sr + 64) < 544;
    const unsigned short* bp0 = W + (size_t)(n0 + sr) * DI + sc * 8;
    const unsigned short* bp1 = W + (size_t)(n0 + sr + 64) * DI + sc * 8;
    f32x4 acc[4][4] = {};
    int q = lane >> 4, ml = lane & 15;
    for (int k0 = 0; k0 < DI; k0 += 32) {
        uint4 a0 = *(const uint4*)(ap0 + k0);
        uint4 a1 = *(const uint4*)(ap1 + k0);
        uint4 b0 = make_uint4(0u, 0u, 0u, 0u), b1 = make_uint4(0u, 0u, 0u, 0u);
        if (bv0) b0 = *(const uint4*)(bp0 + k0);
        if (bv1) b1 = *(const uint4*)(bp1 + k0);
        __syncthreads();
        *(uint4*)&As[sr][sc * 8]      = a0;
        *(uint4*)&As[sr + 64][sc * 8] = a1;
        *(uint4*)&Bs[sr][sc * 8]      = b0;
        *(uint4*)&Bs[sr + 64][sc * 8] = b1;
        __syncthreads();
        bf16x8 af[4], bfr[4];
        #pragma unroll
        for (int mi = 0; mi < 4; mi++)
            af[mi] = *(const bf16x8*)&As[wm + mi * 16 + ml][q * 8];
        #pragma unroll
        for (int ni = 0; ni < 4; ni++)
            bfr[ni] = *(const bf16x8*)&Bs[wn + ni * 16 + ml][q * 8];
        #pragma unroll
        for (int mi = 0; mi < 4; mi++)
            #pragma unroll
            for (int ni = 0; ni < 4; ni++)
                acc[mi][ni] = __builtin_amdgcn_mfma_f32_16x16x32_bf16(af[mi], bfr[ni], acc[mi][ni], 0, 0, 0);
    }
    #pragma unroll
    for (int mi = 0; mi < 4; mi++) {
        #pragma unroll
        for (int r = 0; r < 4; r++) {
            int mr = m0 + wm + mi * 16 + q * 4 + r;
            #pragma unroll
            for (int ni = 0; ni < 4; ni++) {
                int col = n0 + wn + ni * 16 + ml;
                float v = acc[mi][ni][r];
                if (col < 512) {
                    v += dtb[col];
                    v = (v > 20.f) ? v : log1pf(__expf(v));
                    dt[(size_t)mr * DI + col] = f2bf(v);
                } else if (col < 544) {
                    db[(size_t)mr * 32 + (col - 512)] = v;
                }
            }
        }
    }
}

// ---------------------------------------------------------------------------
// scan phase 1 (x2 vectorized in d): each thread handles d and d+1.
// ---------------------------------------------------------------------------
__global__ __launch_bounds__(256) void k_scan_p1(const unsigned short* __restrict__ dt,
                                                 const unsigned short* __restrict__ x,
                                                 const float* __restrict__ db,
                                                 const float* __restrict__ Alog,
                                                 float* __restrict__ hS,
                                                 float* __restrict__ csum) {
    int gid = blockIdx.x * 256 + threadIdx.x;   // (bl*CH + c)*256 + dp
    int dp = gid & 255;
    int d = dp * 2;
    int bcix = gid >> 8;
    int c = bcix & (CH - 1);
    int bl = bcix >> 6;
    float A0[DS], A1[DS], h0[DS], h1[DS];
    #pragma unroll
    for (int n = 0; n < DS; n++) {
        A0[n] = -__expf(Alog[d * DS + n]);
        A1[n] = -__expf(Alog[(d + 1) * DS + n]);
        h0[n] = 0.f; h1[n] = 0.f;
    }
    int tbase = c * CLEN;
    const unsigned int* dtp = (const unsigned int*)(dt + ((size_t)bl * T_LR + tbase) * DI + d);
    const unsigned int* xp  = (const unsigned int*)(x  + ((size_t)bl * T_LR + tbase) * DI + d);
    const float* bcp = db + ((size_t)bl * T_LR + tbase) * 32;
    float S0 = 0.f, S1 = 0.f;
    for (int t = 0; t < CLEN; t++) {
        unsigned int dw = dtp[(size_t)t * (DI / 2)];
        unsigned int xw = xp[(size_t)t * (DI / 2)];
        float dt0 = bf2f((unsigned short)(dw & 0xffff));
        float dt1 = bf2f((unsigned short)(dw >> 16));
        float x0 = bf2f((unsigned short)(xw & 0xffff));
        float x1 = bf2f((unsigned short)(xw >> 16));
        float dtx0 = dt0 * x0, dtx1 = dt1 * x1;
        const float* bc = bcp + (size_t)t * 32;
        S0 += dt0; S1 += dt1;
        #pragma unroll
        for (int n = 0; n < DS; n++) {
            float bn = bc[n];
            h0[n] = __expf(dt0 * A0[n]) * h0[n] + dtx0 * bn;
            h1[n] = __expf(dt1 * A1[n]) * h1[n] + dtx1 * bn;
        }
    }
    size_t base = (size_t)(bl * CH + c) * DI + d;
    float* hp0 = hS + base * DS;
    float* hp1 = hS + (base + 1) * DS;
    #pragma unroll
    for (int n = 0; n < DS; n++) { hp0[n] = h0[n]; hp1[n] = h1[n]; }
    csum[base] = S0;
    csum[base + 1] = S1;
}

// ---------------------------------------------------------------------------
// scan phase 2: per (bl, d, n) thread; sequential over CH chunks, in place.
// ---------------------------------------------------------------------------
__global__ __launch_bounds__(256) void k_scan_p2(float* __restrict__ hS,
                                                 const float* __restrict__ csum,
                                                 const float* __restrict__ Alog) {
    int gid = blockIdx.x * 256 + threadIdx.x;   // (bl*DI + d)*DS + n
    int n = gid & (DS - 1);
    int d = (gid >> 4) & (DI - 1);
    int bl = gid >> 13;
    float An = -__expf(Alog[d * DS + n]);
    float hs = 0.f;
    for (int c = 0; c < CH; c++) {
        size_t base = ((size_t)(bl * CH + c) * DI + d);
        float he = hS[base * DS + n];
        float S  = csum[base];
        hS[base * DS + n] = hs;
        hs = __expf(An * S) * hs + he;
    }
}

// ---------------------------------------------------------------------------
// scan phase 3 (x2 vectorized in d): y written bf16 (packed uint) over x.
// ---------------------------------------------------------------------------
__global__ __launch_bounds__(256) void k_scan_p3(const unsigned short* __restrict__ dt,
                                                 unsigned short* x,
                                                 const float* __restrict__ db,
                                                 const float* __restrict__ Alog,
                                                 const float* __restrict__ Dp,
                                                 const float* __restrict__ hS) {
    int gid = blockIdx.x * 256 + threadIdx.x;   // (bl*CH + c)*256 + dp
    int dp = gid & 255;
    int d = dp * 2;
    int bcix = gid >> 8;
    int c = bcix & (CH - 1);
    int bl = bcix >> 6;
    float A0[DS], A1[DS], h0[DS], h1[DS];
    size_t base = (size_t)(bl * CH + c) * DI + d;
    const float* hp0 = hS + base * DS;
    const float* hp1 = hS + (base + 1) * DS;
    #pragma unroll
    for (int n = 0; n < DS; n++) {
        A0[n] = -__expf(Alog[d * DS + n]);
        A1[n] = -__expf(Alog[(d + 1) * DS + n]);
        h0[n] = hp0[n]; h1[n] = hp1[n];
    }
    float Dd0 = Dp[d], Dd1 = Dp[d + 1];
    int tbase = c * CLEN;
    const unsigned int* dtp = (const unsigned int*)(dt + ((size_t)bl * T_LR + tbase) * DI + d);
    unsigned int* xp = (unsigned int*)(x + ((size_t)bl * T_LR + tbase) * DI + d);
    const float* bcp = db + ((size_t)bl * T_LR + tbase) * 32;
    for (int t = 0; t < CLEN; t++) {
        unsigned int dw = dtp[(size_t)t * (DI / 2)];
        unsigned int xw = xp[(size_t)t * (DI / 2)];
        float dt0 = bf2f((unsigned short)(dw & 0xffff));
        float dt1 = bf2f((unsigned short)(dw >> 16));
        float x0 = bf2f((unsigned short)(xw & 0xffff));
        float x1 = bf2f((unsigned short)(xw >> 16));
        float dtx0 = dt0 * x0, dtx1 = dt1 * x1;
        const float* bc = bcp + (size_t)t * 32;
        float acc0 = 0.f, acc1 = 0.f;
        #pragma unroll
        for (int n = 0; n < DS; n++) {
            float bn = bc[n], cn = bc[16 + n];
            h0[n] = __expf(dt0 * A0[n]) * h0[n] + dtx0 * bn;
            h1[n] = __expf(dt1 * A1[n]) * h1[n] + dtx1 * bn;
            acc0 += h0[n] * cn;
            acc1 += h1[n] * cn;
        }
        float y0 = acc0 + x0 * Dd0, y1 = acc1 + x1 * Dd1;
        xp[(size_t)t * (DI / 2)] = (unsigned int)f2bf(y0) | ((unsigned int)f2bf(y1) << 16);
    }
}

// ---------------------------------------------------------------------------
extern "C" void kernel_launch(void* const* d_in, const int* in_sizes, int n_in,
                              void* d_out, int out_size, void* d_ws, size_t ws_size,
                              hipStream_t stream) {
    const float* x       = (const float*)d_in[0];
    const float* enc_w1  = (const float*)d_in[1];
    const float* enc_b1  = (const float*)d_in[2];
    const float* enc_w2  = (const float*)d_in[3];
    const float* enc_b2  = (const float*)d_in[4];
    const float* norm1_w = (const float*)d_in[5];
    const float* norm2_w = (const float*)d_in[6];
    const float* convd_w = (const float*)d_in[25];
    const float* convd_b = (const float*)d_in[26];
    const float* bn_g    = (const float*)d_in[27];
    const float* bn_b    = (const float*)d_in[28];
    const float* bn_mean = (const float*)d_in[29];
    const float* bn_var  = (const float*)d_in[30];
    const float* sp_w    = (const float*)d_in[31];
    const float* sp_b    = (const float*)d_in[32];
    float* out = (float*)d_out;

    // ---- workspace layout (float slots) ----
    float* ws = (float*)d_ws;
    size_t availf = ws_size / sizeof(float);
    size_t o = 0;
    float* t_buf  = ws + o; o += (size_t)BT * DM;
    float* xn_buf = ws + o; o += (size_t)BT * DM;       // later: comb_bf overlay
    float* mo     = ws + o; o += (size_t)BT * DM;       // early: xt/e1t; late: d_bf overlay
    unsigned short* xn_bf = (unsigned short*)(ws + o); o += (size_t)BT * DM / 2;
    unsigned short* tb_bf = (unsigned short*)(ws + o); o += (size_t)BT * DM / 2;
    unsigned short* inW_bf  = (unsigned short*)(ws + o); o += (1024 * DM) / 2;
    unsigned short* outW_bf = (unsigned short*)(ws + o); o += (DM * DI) / 2;
    unsigned short* WcAll   = (unsigned short*)(ws + o); o += (544 * DI) / 2;
    unsigned short* W1r  = (unsigned short*)(ws + o); o += (3 * 128 * 64) / 2;
    unsigned short* W2r  = (unsigned short*)(ws + o); o += (3 * 256 * 128) / 2;
    unsigned short* Wdr  = (unsigned short*)(ws + o); o += (3 * 256 * 512) / 2;
    unsigned short* Wspr = (unsigned short*)(ws + o); o += (3 * 128 * 256) / 2;
    float* alpha_d = ws + o; o += 256;
    float* beta_d  = ws + o; o += 256;
    size_t persist = o;
    float* scratch = ws + persist;
    size_t scratch_avail = (availf > persist) ? (availf - persist) : 0;
    // per-batch scratch (float slots): xcs bf16 + dt bf16 + db f32 + hS + csum
    size_t per_b = (size_t)T_LR * DI / 2 * 2 + (size_t)T_LR * 32
                 + (size_t)CH * DI * (DS + 1);
    int Bc = 16;
    while (Bc > 1 && (size_t)Bc * per_b > scratch_avail) Bc >>= 1;

    // encoder temporaries overlay mo (dead until out_proj accumulation)
    unsigned short* xt  = (unsigned short*)mo;                         // (b,T,64) bf16
    unsigned short* e1t = (unsigned short*)(mo + (size_t)BT * 64 / 2); // (b,T,128) bf16
    unsigned short* comb_bf = (unsigned short*)xn_buf;   // overlay after xn dead
    unsigned short* d_bf = (unsigned short*)mo;          // overlay after mo dead

    // weight prep
    k_wrearr<<<(128 * 64 + 255) / 256, 256, 0, stream>>>(enc_w1, W1r, 128, 64);
    k_wrearr<<<(256 * 128 + 255) / 256, 256, 0, stream>>>(enc_w2, W2r, 256, 128);
    k_wrearr<<<(256 * 512 + 255) / 256, 256, 0, stream>>>(convd_w, Wdr, 256, 512);
    k_wrearr<<<(128 * 256 + 255) / 256, 256, 0, stream>>>(sp_w, Wspr, 128, 256);
    k_bnfold<<<1, 256, 0, stream>>>(convd_b, bn_g, bn_b, bn_mean, bn_var, alpha_d, beta_d);

    // encoder
    k_transp<<<dim3(T_LR / 32, 2, B_SZ), 256, 0, stream>>>(x, xt, 64);
    k_conv3_bf<<<dim3(BT / 128, 1), 256, 0, stream>>>(xt, 64, nullptr, 0, W1r,
                                                      nullptr, enc_b1, nullptr, e1t, 128, 1, 0);
    k_conv3_bf<<<dim3(BT / 128, 2), 256, 0, stream>>>(e1t, 128, nullptr, 0, W2r,
                                                      nullptr, enc_b2, t_buf, tb_bf, 256, 1, 0);
    k_rmsnorm<<<BT / 4, 256, 0, stream>>>(t_buf, norm1_w, xn_buf, xn_bf, BT);

    for (int dir = 0; dir < 2; dir++) {
        const float* inW   = (const float*)d_in[7 + 9 * dir];
        const float* convW = (const float*)d_in[8 + 9 * dir];
        const float* convb = (const float*)d_in[9 + 9 * dir];
        const float* xW    = (const float*)d_in[10 + 9 * dir];
        const float* dtW   = (const float*)d_in[11 + 9 * dir];
        const float* dtb   = (const float*)d_in[12 + 9 * dir];
        const float* Alog  = (const float*)d_in[13 + 9 * dir];
        const float* Dp    = (const float*)d_in[14 + 9 * dir];
        const float* outW  = (const float*)d_in[15 + 9 * dir];
        int rev = dir;
        k_cast<<<(1024 * DM) / 256, 256, 0, stream>>>(inW, inW_bf, 1024 * DM);
        k_cast<<<(DM * DI) / 256, 256, 0, stream>>>(outW, outW_bf, DM * DI);
        // WcAll rows 0..511 = dtW@xW[0:16]; rows 512..543 = xW[16:48]
        k_combo<<<(DI * DI) / 256, 256, 0, stream>>>(dtW, xW, WcAll);
        k_cast<<<(32 * DI) / 256, 256, 0, stream>>>(xW + 16 * DI, WcAll + 512 * DI, 32 * DI);
        for (int b0 = 0; b0 < B_SZ; b0 += Bc) {
            int Tc = Bc * T_LR;
            unsigned short* xcs = (unsigned short*)scratch;                       // bf16, later y
            unsigned short* dtb16 = xcs + (size_t)Tc * DI;                        // bf16, later yg
            float* db   = (float*)(dtb16 + (size_t)Tc * DI);
            float* hS   = db + (size_t)Tc * 32;
            float* csum = hS + (size_t)Bc * CH * DI * DS;
            const float*          xnC  = xn_buf + (size_t)b0 * T_LR * DM;
            const unsigned short* xnbC = xn_bf  + (size_t)b0 * T_LR * DM;
            float*                moC  = mo     + (size_t)b0 * T_LR * DM;
            // fused in_proj(xc) + causal dwconv + silu -> xcs bf16
            k_inproj_conv<<<dim3(Tc / 128, DI / 128), 256, 0, stream>>>(
                xnbC, inW_bf, convW, convb, xcs, rev);
            // merged dt (softplus->bf16) + db (fp32) GEMM
            k_gemm_dtdb<<<dim3(Tc / 128, 5), 256, 0, stream>>>(
                xcs, WcAll, dtb16, db, dtb);
            // chunked scan; y bf16 in place over xcs (x2 vectorized)
            k_scan_p1<<<(Bc * CH * 256) / 256, 256, 0, stream>>>(dtb16, xcs, db, Alog, hS, csum);
            k_scan_p2<<<(Bc * DI * DS) / 256, 256, 0, stream>>>(hS, csum, Alog);
            k_scan_p3<<<(Bc * CH * 256) / 256, 256, 0, stream>>>(dtb16, xcs, db, Alog, Dp, hS);
            // z GEMM + gate: yg = bf16(y * silu(z)) -> overlays dt buffer
            k_gemm_bf<<<dim3(Tc / 128, DI / 128), 256, 0, stream>>>(
                xnbC, DM, inW_bf + (size_t)DI * DM, nullptr, dtb16, DI,
                nullptr, nullptr, xcs, DM, DI, 0, rev, 0, 0);
            // mo (+)= yg @ outW^T + xn
            k_gemm_bf<<<dim3(Tc / 128, DM / 128), 256, 0, stream>>>(
                dtb16, DI, outW_bf, moC, nullptr, DM, xnC, nullptr, nullptr,
                DI, DM, 0, 0, rev, dir);
        }
    }

    // combined = rmsnorm(mo) -> comb_bf (xn_buf overlay)
    k_rmsnorm<<<BT / 4, 256, 0, stream>>>(mo, norm2_w, nullptr, comb_bf, BT);
    // convd + bn + silu -> d_bf (mo overlay)
    k_conv3_bf<<<dim3(BT / 128, 2), 256, 0, stream>>>(comb_bf, 256, tb_bf, 256, Wdr,
                                                      alpha_d, beta_d, nullptr, d_bf, 256, 1, 0);
    // sp conv + pixel shuffle -> out
    k_conv3_bf<<<dim3(BT / 128, 1), 256, 0, stream>>>(d_bf, 256, nullptr, 0, Wspr,
                                                      nullptr, sp_b, out, nullptr, 128, 0, 1);
}

// Round 10
// 1889.987 us; speedup vs baseline: 1.1860x; 1.1860x over previous
//
#include <hip/hip_runtime.h>
#include <hip/hip_bf16.h>
#include <math.h>

#define B_SZ 16
#define T_LR 2560
#define BT (B_SZ * T_LR)     // 40960 tokens
#define DM 256               // d_model
#define DI 512               // d_inner
#define DS 16                // d_state
#define DTR 16               // dt_rank
#define CH 64                // scan chunks per sequence
#define CLEN (T_LR / CH)     // 40 steps per chunk

typedef __attribute__((ext_vector_type(8))) short bf16x8;
typedef __attribute__((ext_vector_type(4))) float f32x4;

__device__ __forceinline__ float silu_f(float x) {
    return x / (1.f + __expf(-x));
}
__device__ __forceinline__ unsigned short f2bf(float v) {
    __hip_bfloat16 h = __float2bfloat16(v);
    return *(unsigned short*)&h;
}
__device__ __forceinline__ float bf2f(unsigned short u) {
    union { unsigned int i; float f; } c;
    c.i = (unsigned int)u << 16;
    return c.f;
}
__device__ __forceinline__ int seqrev(int r) {
    int s = r / T_LR, t = r % T_LR;
    return s * T_LR + (T_LR - 1 - t);
}

// ---------------------------------------------------------------------------
// transpose (b,nch,T) f32 -> (b,T,nch) bf16
// ---------------------------------------------------------------------------
__global__ __launch_bounds__(256) void k_transp(const float* __restrict__ in,
                                                unsigned short* __restrict__ outb,
                                                int nch) {
    __shared__ float s[32][33];
    int b = blockIdx.z;
    int t0 = blockIdx.x * 32, c0 = blockIdx.y * 32;
    int tx = threadIdx.x & 31, ty = threadIdx.x >> 5;   // 32 x 8
    #pragma unroll
    for (int j = 0; j < 4; j++) {
        int c = c0 + ty + j * 8;
        s[ty + j * 8][tx] = in[((size_t)b * nch + c) * T_LR + t0 + tx];
    }
    __syncthreads();
    #pragma unroll
    for (int j = 0; j < 4; j++) {
        int t = t0 + ty + j * 8;
        outb[((size_t)b * T_LR + t) * nch + c0 + tx] = f2bf(s[tx][ty + j * 8]);
    }
}

// ---------------------------------------------------------------------------
// weight rearrange: in (N,K,3) f32 -> out [3][N][K] bf16
// ---------------------------------------------------------------------------
__global__ __launch_bounds__(256) void k_wrearr(const float* __restrict__ in,
                                                unsigned short* __restrict__ out,
                                                int N, int K) {
    int i = blockIdx.x * 256 + threadIdx.x;     // n*K + ci
    if (i >= N * K) return;
    int n = i / K, ci = i % K;
    #pragma unroll
    for (int k = 0; k < 3; k++)
        out[((size_t)k * N + n) * K + ci] = f2bf(in[((size_t)n * K + ci) * 3 + k]);
}

// ---------------------------------------------------------------------------
// fold BN into alpha/beta (256 ch): v = alpha*conv + beta
// ---------------------------------------------------------------------------
__global__ __launch_bounds__(256) void k_bnfold(const float* __restrict__ cb,
                                                const float* __restrict__ bng,
                                                const float* __restrict__ bnb,
                                                const float* __restrict__ bnm,
                                                const float* __restrict__ bnv,
                                                float* __restrict__ alpha,
                                                float* __restrict__ beta) {
    int c = threadIdx.x;
    float a = bng[c] * rsqrtf(bnv[c] + 1e-5f);
    alpha[c] = a;
    beta[c] = (cb[c] - bnm[c]) * a + bnb[c];
}

// ---------------------------------------------------------------------------
// dual-dir f32 -> bf16 cast: dst[0:n) = bf(s0), dst[n:2n) = bf(s1)
// ---------------------------------------------------------------------------
__global__ __launch_bounds__(256) void k_cast2(const float* __restrict__ s0,
                                               const float* __restrict__ s1,
                                               unsigned short* __restrict__ d, int n) {
    int i = blockIdx.x * 256 + threadIdx.x;
    if (i < n) { d[i] = f2bf(s0[i]); d[n + i] = f2bf(s1[i]); }
}

// ---------------------------------------------------------------------------
// dual-dir combo weight: Wc[z][n][k] = sum_j dtW_z[n][j] * xW_z[j][k]
// ---------------------------------------------------------------------------
__global__ __launch_bounds__(256) void k_combo2(const float* __restrict__ dtW0,
                                                const float* __restrict__ dtW1,
                                                const float* __restrict__ xW0,
                                                const float* __restrict__ xW1,
                                                unsigned short* __restrict__ Wc) {
    int z = blockIdx.y;
    const float* dtW = z ? dtW1 : dtW0;
    const float* xW  = z ? xW1  : xW0;
    int i = blockIdx.x * 256 + threadIdx.x;   // n*512 + k
    int n = i >> 9, k = i & 511;
    float v = 0.f;
    #pragma unroll
    for (int j = 0; j < 16; j++) v += dtW[n * 16 + j] * xW[j * 512 + k];
    Wc[(size_t)z * DI * DI + i] = f2bf(v);
}

// ---------------------------------------------------------------------------
// implicit-GEMM k=3 "same" conv via MFMA (encoder/decoder convs).
// ---------------------------------------------------------------------------
__global__ __launch_bounds__(256) void k_conv3_bf(const unsigned short* __restrict__ A1, int K1,
                                                  const unsigned short* __restrict__ A2, int K2,
                                                  const unsigned short* __restrict__ W,
                                                  const float* __restrict__ alpha,
                                                  const float* __restrict__ beta,
                                                  float* __restrict__ outf,
                                                  unsigned short* __restrict__ outb,
                                                  int N, int dosilu, int pixsh) {
    int Kt = K1 + K2;
    __shared__ unsigned short As[130][40];
    __shared__ unsigned short Bs[3][128][40];
    int tid = threadIdx.x;
    int wave = tid >> 6, lane = tid & 63;
    int wm = (wave >> 1) * 64, wn = (wave & 1) * 64;
    int m0 = blockIdx.x * 128, n0 = blockIdx.y * 128;
    int b = m0 / T_LR, t0 = m0 % T_LR;
    int q = lane >> 4, ml = lane & 15;
    f32x4 acc[4][4] = {};
    for (int k0 = 0; k0 < Kt; k0 += 32) {
        __syncthreads();
        for (int i = tid; i < 520; i += 256) {
            int row = i >> 2, cq = i & 3;
            int t = t0 - 1 + row;
            uint4 v = make_uint4(0u, 0u, 0u, 0u);
            if (t >= 0 && t < T_LR) {
                int col = k0 + cq * 8;
                const unsigned short* src = (col < K1)
                    ? A1 + (size_t)(b * T_LR + t) * K1 + col
                    : A2 + (size_t)(b * T_LR + t) * K2 + (col - K1);
                v = *(const uint4*)src;
            }
            *(uint4*)&As[row][cq * 8] = v;
        }
        for (int i = tid; i < 1536; i += 256) {
            int tap = i >> 9;
            int r = (i >> 2) & 127;
            int cq = i & 3;
            *(uint4*)&Bs[tap][r][cq * 8] =
                *(const uint4*)(W + ((size_t)tap * N + n0 + r) * Kt + k0 + cq * 8);
        }
        __syncthreads();
        #pragma unroll
        for (int tap = 0; tap < 3; tap++) {
            bf16x8 bfr[4];
            #pragma unroll
            for (int ni = 0; ni < 4; ni++)
                bfr[ni] = *(const bf16x8*)&Bs[tap][wn + ni * 16 + ml][q * 8];
            #pragma unroll
            for (int mi = 0; mi < 4; mi++) {
                bf16x8 af = *(const bf16x8*)&As[wm + mi * 16 + ml + tap][q * 8];
                #pragma unroll
                for (int ni = 0; ni < 4; ni++)
                    acc[mi][ni] = __builtin_amdgcn_mfma_f32_16x16x32_bf16(af, bfr[ni], acc[mi][ni], 0, 0, 0);
            }
        }
    }
    #pragma unroll
    for (int mi = 0; mi < 4; mi++) {
        #pragma unroll
        for (int r = 0; r < 4; r++) {
            int mr = m0 + wm + mi * 16 + q * 4 + r;
            int t = mr - b * T_LR;
            #pragma unroll
            for (int ni = 0; ni < 4; ni++) {
                int col = n0 + wn + ni * 16 + ml;
                float a = alpha ? alpha[col] : 1.f;
                float v = acc[mi][ni][r] * a + beta[col];
                if (dosilu) v = silu_f(v);
                if (pixsh) {
                    int c2 = col >> 1, rr = col & 1;
                    outf[(((size_t)b * 64 + c2) * T_LR + t) * 2 + rr] = v;
                } else {
                    size_t o = (size_t)mr * N + col;
                    if (outf) outf[o] = v;
                    if (outb) outb[o] = f2bf(v);
                }
            }
        }
    }
}

// ---------------------------------------------------------------------------
// dir-folded fused in_proj (xc half) + causal dwconv k=4 + silu -> xcs bf16.
// z = blockIdx.z selects direction (arev = z).
// ---------------------------------------------------------------------------
__global__ __launch_bounds__(256) void k_inproj_conv2(const unsigned short* __restrict__ xn,
                                                      const unsigned short* __restrict__ inW_b,
                                                      const float* __restrict__ cw0,
                                                      const float* __restrict__ cw1,
                                                      const float* __restrict__ cb0,
                                                      const float* __restrict__ cb1,
                                                      unsigned short* xcs_b, size_t xcsStr) {
    int z = blockIdx.z;
    const unsigned short* inW = inW_b + (size_t)z * 1024 * DM;
    const float* cw = z ? cw1 : cw0;
    const float* cb = z ? cb1 : cb0;
    unsigned short* xcs = xcs_b + (size_t)z * xcsStr;
    int arev = z;
    __shared__ unsigned short As[128][40];
    __shared__ unsigned short Bs[128][40];
    __shared__ unsigned short Ct[131][136];   // rows: internal t0-3 .. t0+127
    int tid = threadIdx.x;
    int wave = tid >> 6, lane = tid & 63;
    int wm = (wave >> 1) * 64, wn = (wave & 1) * 64;
    int m0 = blockIdx.x * 128, n0 = blockIdx.y * 128;
    int b = m0 / T_LR, t0 = m0 % T_LR;
    int sc = tid & 3, sr = tid >> 2;
    int ar0 = m0 + sr, ar1 = m0 + sr + 64;
    if (arev) { ar0 = seqrev(ar0); ar1 = seqrev(ar1); }
    const unsigned short* ap0 = xn + (size_t)ar0 * DM + sc * 8;
    const unsigned short* ap1 = xn + (size_t)ar1 * DM + sc * 8;
    const unsigned short* bp0 = inW + (size_t)(n0 + sr) * DM + sc * 8;
    const unsigned short* bp1 = inW + (size_t)(n0 + sr + 64) * DM + sc * 8;
    f32x4 acc[4][4] = {};
    int q = lane >> 4, ml = lane & 15;
    for (int k0 = 0; k0 < DM; k0 += 32) {
        uint4 a0 = *(const uint4*)(ap0 + k0);
        uint4 a1 = *(const uint4*)(ap1 + k0);
        uint4 b0 = *(const uint4*)(bp0 + k0);
        uint4 b1 = *(const uint4*)(bp1 + k0);
        __syncthreads();
        *(uint4*)&As[sr][sc * 8]      = a0;
        *(uint4*)&As[sr + 64][sc * 8] = a1;
        *(uint4*)&Bs[sr][sc * 8]      = b0;
        *(uint4*)&Bs[sr + 64][sc * 8] = b1;
        __syncthreads();
        bf16x8 af[4], bfr[4];
        #pragma unroll
        for (int mi = 0; mi < 4; mi++)
            af[mi] = *(const bf16x8*)&As[wm + mi * 16 + ml][q * 8];
        #pragma unroll
        for (int ni = 0; ni < 4; ni++)
            bfr[ni] = *(const bf16x8*)&Bs[wn + ni * 16 + ml][q * 8];
        #pragma unroll
        for (int mi = 0; mi < 4; mi++)
            #pragma unroll
            for (int ni = 0; ni < 4; ni++)
                acc[mi][ni] = __builtin_amdgcn_mfma_f32_16x16x32_bf16(af[mi], bfr[ni], acc[mi][ni], 0, 0, 0);
    }
    // main tile -> Ct rows 3..130
    #pragma unroll
    for (int mi = 0; mi < 4; mi++)
        #pragma unroll
        for (int r = 0; r < 4; r++)
            #pragma unroll
            for (int ni = 0; ni < 4; ni++)
                Ct[3 + wm + mi * 16 + q * 4 + r][wn + ni * 16 + ml] = f2bf(acc[mi][ni][r]);
    // halo rows 0..2 via direct dot — 384 items on 256 threads
    for (int i = tid; i < 384; i += 256) {
        int hr = i >> 7, c = i & 127;
        int tr = t0 - 3 + hr;
        float v = 0.f;
        if (tr >= 0) {
            int src = b * T_LR + (arev ? (T_LR - 1 - tr) : tr);
            const unsigned short* xr = xn + (size_t)src * DM;
            const unsigned short* wr = inW + (size_t)(n0 + c) * DM;
            for (int k = 0; k < DM; k += 8) {
                uint4 xa = *(const uint4*)(xr + k);
                uint4 wa = *(const uint4*)(wr + k);
                const unsigned short* xs = (const unsigned short*)&xa;
                const unsigned short* wsp = (const unsigned short*)&wa;
                #pragma unroll
                for (int j = 0; j < 8; j++) v += bf2f(xs[j]) * bf2f(wsp[j]);
            }
        }
        Ct[hr][c] = f2bf(v);
    }
    __syncthreads();
    // causal conv k=4 + silu, write xcs bf16
    int col = tid & 127;
    int d = n0 + col;
    float w0 = cw[d * 4 + 0], w1 = cw[d * 4 + 1], w2 = cw[d * 4 + 2], w3 = cw[d * 4 + 3];
    float bi = cb[d];
    int rbase = tid >> 7;
    for (int j = 0; j < 64; j++) {
        int row = rbase + 2 * j;
        float v = bi + bf2f(Ct[row][col]) * w0 + bf2f(Ct[row + 1][col]) * w1
                     + bf2f(Ct[row + 2][col]) * w2 + bf2f(Ct[row + 3][col]) * w3;
        xcs[(size_t)(m0 + row) * DI + d] = f2bf(silu_f(v));
    }
}

// ---------------------------------------------------------------------------
// rmsnorm over last dim (256). One wave per token. fp32 and/or bf16 out.
// ---------------------------------------------------------------------------
__global__ __launch_bounds__(256) void k_rmsnorm(const float* __restrict__ in1,
                                                 const float* __restrict__ w,
                                                 float* __restrict__ out,
                                                 unsigned short* __restrict__ out_bf,
                                                 int ntok) {
    int tok = (blockIdx.x * 256 + threadIdx.x) >> 6;
    int lane = threadIdx.x & 63;
    if (tok >= ntok) return;
    float4 v = ((const float4*)(in1 + (size_t)tok * DM))[lane];
    float ss = v.x * v.x + v.y * v.y + v.z * v.z + v.w * v.w;
    #pragma unroll
    for (int off = 32; off > 0; off >>= 1) ss += __shfl_xor(ss, off);
    float sc = rsqrtf(ss * (1.f / 256.f) + 1e-6f);
    float4 wv = ((const float4*)w)[lane];
    float4 o;
    o.x = v.x * sc * wv.x; o.y = v.y * sc * wv.y;
    o.z = v.z * sc * wv.z; o.w = v.w * sc * wv.w;
    if (out) ((float4*)(out + (size_t)tok * DM))[lane] = o;
    if (out_bf) {
        ushort4 ob;
        ob.x = f2bf(o.x); ob.y = f2bf(o.y); ob.z = f2bf(o.z); ob.w = f2bf(o.w);
        ((ushort4*)(out_bf + (size_t)tok * DM))[lane] = ob;
    }
}

// ---------------------------------------------------------------------------
// generic bf16 MFMA GEMM (round-8 form; used for out_proj).
// ---------------------------------------------------------------------------
__global__ __launch_bounds__(256) void k_gemm_bf(const unsigned short* __restrict__ A, int lda,
                                                 const unsigned short* __restrict__ Bw,
                                                 float* Cf, unsigned short* Cb, int ldc,
                                                 const float* __restrict__ res,
                                                 const float* __restrict__ bias,
                                                 const unsigned short* __restrict__ gate,
                                                 int K, int Nout, int act,
                                                 int arev, int crev, int accum) {
    __shared__ unsigned short As[128][40];
    __shared__ unsigned short Bs[128][40];
    int tid = threadIdx.x;
    int wave = tid >> 6, lane = tid & 63;
    int wm = (wave >> 1) * 64, wn = (wave & 1) * 64;
    int m0 = blockIdx.x * 128, n0 = blockIdx.y * 128;
    int sc = tid & 3, sr = tid >> 2;
    int ar0 = m0 + sr, ar1 = m0 + sr + 64;
    if (arev) { ar0 = seqrev(ar0); ar1 = seqrev(ar1); }
    const unsigned short* ap0 = A + (size_t)ar0 * lda + sc * 8;
    const unsigned short* ap1 = A + (size_t)ar1 * lda + sc * 8;
    bool bv0 = (n0 + sr) < Nout;
    bool bv1 = (n0 + sr + 64) < Nout;
    const unsigned short* bp0 = Bw + (size_t)(n0 + sr) * K + sc * 8;
    const unsigned short* bp1 = Bw + (size_t)(n0 + sr + 64) * K + sc * 8;
    f32x4 acc[4][4] = {};
    int q = lane >> 4, ml = lane & 15;
    for (int k0 = 0; k0 < K; k0 += 32) {
        uint4 a0 = *(const uint4*)(ap0 + k0);
        uint4 a1 = *(const uint4*)(ap1 + k0);
        uint4 b0 = make_uint4(0u, 0u, 0u, 0u), b1 = make_uint4(0u, 0u, 0u, 0u);
        if (bv0) b0 = *(const uint4*)(bp0 + k0);
        if (bv1) b1 = *(const uint4*)(bp1 + k0);
        __syncthreads();
        *(uint4*)&As[sr][sc * 8]      = a0;
        *(uint4*)&As[sr + 64][sc * 8] = a1;
        *(uint4*)&Bs[sr][sc * 8]      = b0;
        *(uint4*)&Bs[sr + 64][sc * 8] = b1;
        __syncthreads();
        bf16x8 af[4], bfr[4];
        #pragma unroll
        for (int mi = 0; mi < 4; mi++)
            af[mi] = *(const bf16x8*)&As[wm + mi * 16 + ml][q * 8];
        #pragma unroll
        for (int ni = 0; ni < 4; ni++)
            bfr[ni] = *(const bf16x8*)&Bs[wn + ni * 16 + ml][q * 8];
        #pragma unroll
        for (int mi = 0; mi < 4; mi++)
            #pragma unroll
            for (int ni = 0; ni < 4; ni++)
                acc[mi][ni] = __builtin_amdgcn_mfma_f32_16x16x32_bf16(af[mi], bfr[ni], acc[mi][ni], 0, 0, 0);
    }
    #pragma unroll
    for (int mi = 0; mi < 4; mi++) {
        #pragma unroll
        for (int r = 0; r < 4; r++) {
            int mr = m0 + wm + mi * 16 + q * 4 + r;
            int orow = crev ? seqrev(mr) : mr;
            #pragma unroll
            for (int ni = 0; ni < 4; ni++) {
                int col = n0 + wn + ni * 16 + ml;
                if (col < Nout) {
                    float v = acc[mi][ni][r];
                    if (bias) v += bias[col];
                    if (act == 2) v = (v > 20.f) ? v : log1pf(__expf(v));
                    if (gate) v = silu_f(v) * bf2f(gate[(size_t)mr * ldc + col]);
                    if (res) v += res[(size_t)orow * ldc + col];
                    if (accum) v += Cf[(size_t)orow * ldc + col];
                    if (Cf) Cf[(size_t)orow * ldc + col] = v;
                    if (Cb) Cb[(size_t)orow * ldc + col] = f2bf(v);
                }
            }
        }
    }
}

// ---------------------------------------------------------------------------
// dir-folded bf16 MFMA GEMM: z = blockIdx.z selects direction.
// A = A_b + z*aStr; Bw = Bw_b + z*bStr; Cf/Cb/gate likewise; bias0/bias1.
// arevz: if set, arev = z. No res/crev/accum (not needed in folded calls).
// ---------------------------------------------------------------------------
__global__ __launch_bounds__(256) void k_gemm_bf2(const unsigned short* __restrict__ A_b, size_t aStr,
                                                  const unsigned short* __restrict__ Bw_b, size_t bStr,
                                                  float* Cf_b, size_t cfStr,
                                                  unsigned short* Cb_b, size_t cbStr,
                                                  const float* __restrict__ bias0,
                                                  const float* __restrict__ bias1,
                                                  const unsigned short* __restrict__ gate_b, size_t gStr,
                                                  int lda, int ldc, int K, int Nout, int act, int arevz) {
    int z = blockIdx.z;
    const unsigned short* A = A_b + (size_t)z * aStr;
    const unsigned short* Bw = Bw_b + (size_t)z * bStr;
    float* Cf = Cf_b ? Cf_b + (size_t)z * cfStr : nullptr;
    unsigned short* Cb = Cb_b ? Cb_b + (size_t)z * cbStr : nullptr;
    const float* bias = bias0 ? (z ? bias1 : bias0) : nullptr;
    const unsigned short* gate = gate_b ? gate_b + (size_t)z * gStr : nullptr;
    int arev = arevz ? z : 0;
    __shared__ unsigned short As[128][40];
    __shared__ unsigned short Bs[128][40];
    int tid = threadIdx.x;
    int wave = tid >> 6, lane = tid & 63;
    int wm = (wave >> 1) * 64, wn = (wave & 1) * 64;
    int m0 = blockIdx.x * 128, n0 = blockIdx.y * 128;
    int sc = tid & 3, sr = tid >> 2;
    int ar0 = m0 + sr, ar1 = m0 + sr + 64;
    if (arev) { ar0 = seqrev(ar0); ar1 = seqrev(ar1); }
    const unsigned short* ap0 = A + (size_t)ar0 * lda + sc * 8;
    const unsigned short* ap1 = A + (size_t)ar1 * lda + sc * 8;
    bool bv0 = (n0 + sr) < Nout;
    bool bv1 = (n0 + sr + 64) < Nout;
    const unsigned short* bp0 = Bw + (size_t)(n0 + sr) * K + sc * 8;
    const unsigned short* bp1 = Bw + (size_t)(n0 + sr + 64) * K + sc * 8;
    f32x4 acc[4][4] = {};
    int q = lane >> 4, ml = lane & 15;
    for (int k0 = 0; k0 < K; k0 += 32) {
        uint4 a0 = *(const uint4*)(ap0 + k0);
        uint4 a1 = *(const uint4*)(ap1 + k0);
        uint4 b0 = make_uint4(0u, 0u, 0u, 0u), b1 = make_uint4(0u, 0u, 0u, 0u);
        if (bv0) b0 = *(const uint4*)(bp0 + k0);
        if (bv1) b1 = *(const uint4*)(bp1 + k0);
        __syncthreads();
        *(uint4*)&As[sr][sc * 8]      = a0;
        *(uint4*)&As[sr + 64][sc * 8] = a1;
        *(uint4*)&Bs[sr][sc * 8]      = b0;
        *(uint4*)&Bs[sr + 64][sc * 8] = b1;
        __syncthreads();
        bf16x8 af[4], bfr[4];
        #pragma unroll
        for (int mi = 0; mi < 4; mi++)
            af[mi] = *(const bf16x8*)&As[wm + mi * 16 + ml][q * 8];
        #pragma unroll
        for (int ni = 0; ni < 4; ni++)
            bfr[ni] = *(const bf16x8*)&Bs[wn + ni * 16 + ml][q * 8];
        #pragma unroll
        for (int mi = 0; mi < 4; mi++)
            #pragma unroll
            for (int ni = 0; ni < 4; ni++)
                acc[mi][ni] = __builtin_amdgcn_mfma_f32_16x16x32_bf16(af[mi], bfr[ni], acc[mi][ni], 0, 0, 0);
    }
    #pragma unroll
    for (int mi = 0; mi < 4; mi++) {
        #pragma unroll
        for (int r = 0; r < 4; r++) {
            int mr = m0 + wm + mi * 16 + q * 4 + r;
            #pragma unroll
            for (int ni = 0; ni < 4; ni++) {
                int col = n0 + wn + ni * 16 + ml;
                if (col < Nout) {
                    float v = acc[mi][ni][r];
                    if (bias) v += bias[col];
                    if (act == 2) v = (v > 20.f) ? v : log1pf(__expf(v));
                    if (gate) v = silu_f(v) * bf2f(gate[(size_t)mr * ldc + col]);
                    if (Cf) Cf[(size_t)mr * ldc + col] = v;
                    if (Cb) Cb[(size_t)mr * ldc + col] = f2bf(v);
                }
            }
        }
    }
}

// ---------------------------------------------------------------------------
// scan phase 1 (dir-folded via blockIdx.y): chunk-local scan from h=0.
// dt, x bf16 (stride DI); db fp32 (stride 32: B=0..16, C=16..32)
// ---------------------------------------------------------------------------
__global__ __launch_bounds__(256) void k_scan_p1(const unsigned short* __restrict__ dt_b,
                                                 const unsigned short* __restrict__ x_b,
                                                 const float* __restrict__ db_b,
                                                 const float* __restrict__ Alog0,
                                                 const float* __restrict__ Alog1,
                                                 float* __restrict__ hS_b,
                                                 float* __restrict__ csum_b,
                                                 size_t dxStr, size_t dbStr,
                                                 size_t hStr, size_t cStr) {
    int z = blockIdx.y;
    const unsigned short* dtB = dt_b + (size_t)z * dxStr;
    const unsigned short* xB  = x_b  + (size_t)z * dxStr;
    const float* dbB = db_b + (size_t)z * dbStr;
    const float* Alog = z ? Alog1 : Alog0;
    float* hS = hS_b + (size_t)z * hStr;
    float* csum = csum_b + (size_t)z * cStr;
    int gid = blockIdx.x * 256 + threadIdx.x;   // (bl*CH + c)*DI + d
    int d = gid & (DI - 1);
    int bcix = gid >> 9;
    int c = bcix & (CH - 1);
    int bl = bcix >> 6;
    float A[DS], h[DS];
    #pragma unroll
    for (int n = 0; n < DS; n++) { A[n] = -__expf(Alog[d * DS + n]); h[n] = 0.f; }
    int tbase = c * CLEN;
    const unsigned short* dtp = dtB + ((size_t)bl * T_LR + tbase) * DI + d;
    const unsigned short* xp  = xB  + ((size_t)bl * T_LR + tbase) * DI + d;
    const float* bcp = dbB + ((size_t)bl * T_LR + tbase) * 32;
    float S = 0.f;
    for (int t = 0; t < CLEN; t++) {
        float dtv = bf2f(dtp[(size_t)t * DI]);
        float xv  = bf2f(xp[(size_t)t * DI]);
        float dtx = dtv * xv;
        const float* bc = bcp + (size_t)t * 32;
        S += dtv;
        #pragma unroll
        for (int n = 0; n < DS; n++)
            h[n] = __expf(dtv * A[n]) * h[n] + dtx * bc[n];
    }
    float* hp = hS + (size_t)gid * DS;
    #pragma unroll
    for (int n = 0; n < DS; n++) hp[n] = h[n];
    csum[gid] = S;
}

// ---------------------------------------------------------------------------
// scan phase 2 (dir-folded): sequential over CH chunks, in place.
// ---------------------------------------------------------------------------
__global__ __launch_bounds__(256) void k_scan_p2(float* __restrict__ hS_b,
                                                 const float* __restrict__ csum_b,
                                                 const float* __restrict__ Alog0,
                                                 const float* __restrict__ Alog1,
                                                 size_t hStr, size_t cStr) {
    int z = blockIdx.y;
    float* hS = hS_b + (size_t)z * hStr;
    const float* csum = csum_b + (size_t)z * cStr;
    const float* Alog = z ? Alog1 : Alog0;
    int gid = blockIdx.x * 256 + threadIdx.x;   // (bl*DI + d)*DS + n
    int n = gid & (DS - 1);
    int d = (gid >> 4) & (DI - 1);
    int bl = gid >> 13;
    float An = -__expf(Alog[d * DS + n]);
    float hs = 0.f;
    for (int c = 0; c < CH; c++) {
        size_t base = ((size_t)(bl * CH + c) * DI + d);
        float he = hS[base * DS + n];
        float S  = csum[base];
        hS[base * DS + n] = hs;
        hs = __expf(An * S) * hs + he;
    }
}

// ---------------------------------------------------------------------------
// scan phase 3 (dir-folded): corrected chunk-start state; y bf16 over x.
// ---------------------------------------------------------------------------
__global__ __launch_bounds__(256) void k_scan_p3(const unsigned short* __restrict__ dt_b,
                                                 unsigned short* x_b,
                                                 const float* __restrict__ db_b,
                                                 const float* __restrict__ Alog0,
                                                 const float* __restrict__ Alog1,
                                                 const float* __restrict__ Dp0,
                                                 const float* __restrict__ Dp1,
                                                 const float* __restrict__ hS_b,
                                                 size_t dxStr, size_t dbStr, size_t hStr) {
    int z = blockIdx.y;
    const unsigned short* dtB = dt_b + (size_t)z * dxStr;
    unsigned short* xB = x_b + (size_t)z * dxStr;
    const float* dbB = db_b + (size_t)z * dbStr;
    const float* Alog = z ? Alog1 : Alog0;
    const float* Dp = z ? Dp1 : Dp0;
    const float* hS = hS_b + (size_t)z * hStr;
    int gid = blockIdx.x * 256 + threadIdx.x;   // (bl*CH + c)*DI + d
    int d = gid & (DI - 1);
    int bcix = gid >> 9;
    int c = bcix & (CH - 1);
    int bl = bcix >> 6;
    float A[DS], h[DS];
    const float* hp = hS + (size_t)gid * DS;
    #pragma unroll
    for (int n = 0; n < DS; n++) { A[n] = -__expf(Alog[d * DS + n]); h[n] = hp[n]; }
    float Dd = Dp[d];
    int tbase = c * CLEN;
    const unsigned short* dtp = dtB + ((size_t)bl * T_LR + tbase) * DI + d;
    unsigned short* xp = xB + ((size_t)bl * T_LR + tbase) * DI + d;
    const float* bcp = dbB + ((size_t)bl * T_LR + tbase) * 32;
    for (int t = 0; t < CLEN; t++) {
        float dtv = bf2f(dtp[(size_t)t * DI]);
        float xv  = bf2f(xp[(size_t)t * DI]);
        float dtx = dtv * xv;
        const float* bc = bcp + (size_t)t * 32;
        float acc = 0.f;
        #pragma unroll
        for (int n = 0; n < DS; n++) {
            h[n] = __expf(dtv * A[n]) * h[n] + dtx * bc[n];
            acc += h[n] * bc[16 + n];
        }
        xp[(size_t)t * DI] = f2bf(acc + xv * Dd);
    }
}

// ---------------------------------------------------------------------------
extern "C" void kernel_launch(void* const* d_in, const int* in_sizes, int n_in,
                              void* d_out, int out_size, void* d_ws, size_t ws_size,
                              hipStream_t stream) {
    const float* x       = (const float*)d_in[0];
    const float* enc_w1  = (const float*)d_in[1];
    const float* enc_b1  = (const float*)d_in[2];
    const float* enc_w2  = (const float*)d_in[3];
    const float* enc_b2  = (const float*)d_in[4];
    const float* norm1_w = (const float*)d_in[5];
    const float* norm2_w = (const float*)d_in[6];
    const float* convd_w = (const float*)d_in[25];
    const float* convd_b = (const float*)d_in[26];
    const float* bn_g    = (const float*)d_in[27];
    const float* bn_b    = (const float*)d_in[28];
    const float* bn_mean = (const float*)d_in[29];
    const float* bn_var  = (const float*)d_in[30];
    const float* sp_w    = (const float*)d_in[31];
    const float* sp_b    = (const float*)d_in[32];
    float* out = (float*)d_out;

    // per-direction params
    const float* inW0   = (const float*)d_in[7];
    const float* convW0 = (const float*)d_in[8];
    const float* convb0 = (const float*)d_in[9];
    const float* xW0    = (const float*)d_in[10];
    const float* dtW0   = (const float*)d_in[11];
    const float* dtb0   = (const float*)d_in[12];
    const float* Alog0  = (const float*)d_in[13];
    const float* Dp0    = (const float*)d_in[14];
    const float* outW0  = (const float*)d_in[15];
    const float* inW1   = (const float*)d_in[16];
    const float* convW1 = (const float*)d_in[17];
    const float* convb1 = (const float*)d_in[18];
    const float* xW1    = (const float*)d_in[19];
    const float* dtW1   = (const float*)d_in[20];
    const float* dtb1   = (const float*)d_in[21];
    const float* Alog1  = (const float*)d_in[22];
    const float* Dp1    = (const float*)d_in[23];
    const float* outW1  = (const float*)d_in[24];

    // ---- workspace layout (float slots) ----
    float* ws = (float*)d_ws;
    size_t availf = ws_size / sizeof(float);
    size_t o = 0;
    float* t_buf  = ws + o; o += (size_t)BT * DM;
    float* xn_buf = ws + o; o += (size_t)BT * DM;       // later: comb_bf overlay
    float* mo     = ws + o; o += (size_t)BT * DM;       // early: xt/e1t; late: d_bf overlay
    unsigned short* xn_bf = (unsigned short*)(ws + o); o += (size_t)BT * DM / 2;
    unsigned short* tb_bf = (unsigned short*)(ws + o); o += (size_t)BT * DM / 2;
    unsigned short* inW_bf2  = (unsigned short*)(ws + o); o += (size_t)1024 * DM;      // 2 dirs
    unsigned short* outW_bf2 = (unsigned short*)(ws + o); o += (size_t)DM * DI;        // 2 dirs
    unsigned short* Wcombo2  = (unsigned short*)(ws + o); o += (size_t)DI * DI;        // 2 dirs
    unsigned short* xW_bc2   = (unsigned short*)(ws + o); o += (size_t)32 * DI;        // 2 dirs
    unsigned short* W1r  = (unsigned short*)(ws + o); o += (3 * 128 * 64) / 2;
    unsigned short* W2r  = (unsigned short*)(ws + o); o += (3 * 256 * 128) / 2;
    unsigned short* Wdr  = (unsigned short*)(ws + o); o += (3 * 256 * 512) / 2;
    unsigned short* Wspr = (unsigned short*)(ws + o); o += (3 * 128 * 256) / 2;
    float* alpha_d = ws + o; o += 256;
    float* beta_d  = ws + o; o += 256;
    size_t persist = o;
    float* scratch = ws + persist;
    size_t scratch_avail = (availf > persist) ? (availf - persist) : 0;
    // per-batch-per-dir scratch (float slots): xcs bf16 + dt bf16 + db f32 + hS + csum
    size_t per_b = (size_t)T_LR * DI / 2 * 2 + (size_t)T_LR * 32
                 + (size_t)CH * DI * (DS + 1);
    int Bc = 16;
    while (Bc > 1 && 2 * (size_t)Bc * per_b > scratch_avail) Bc >>= 1;

    // encoder temporaries overlay mo (dead until out_proj accumulation)
    unsigned short* xt  = (unsigned short*)mo;                         // (b,T,64) bf16
    unsigned short* e1t = (unsigned short*)(mo + (size_t)BT * 64 / 2); // (b,T,128) bf16
    unsigned short* comb_bf = (unsigned short*)xn_buf;   // overlay after xn dead
    unsigned short* d_bf = (unsigned short*)mo;          // overlay after mo dead

    // weight prep (both directions up front)
    k_wrearr<<<(128 * 64 + 255) / 256, 256, 0, stream>>>(enc_w1, W1r, 128, 64);
    k_wrearr<<<(256 * 128 + 255) / 256, 256, 0, stream>>>(enc_w2, W2r, 256, 128);
    k_wrearr<<<(256 * 512 + 255) / 256, 256, 0, stream>>>(convd_w, Wdr, 256, 512);
    k_wrearr<<<(128 * 256 + 255) / 256, 256, 0, stream>>>(sp_w, Wspr, 128, 256);
    k_bnfold<<<1, 256, 0, stream>>>(convd_b, bn_g, bn_b, bn_mean, bn_var, alpha_d, beta_d);
    k_cast2<<<(1024 * DM + 255) / 256, 256, 0, stream>>>(inW0, inW1, inW_bf2, 1024 * DM);
    k_cast2<<<(DM * DI + 255) / 256, 256, 0, stream>>>(outW0, outW1, outW_bf2, DM * DI);
    k_cast2<<<(32 * DI + 255) / 256, 256, 0, stream>>>(xW0 + 16 * DI, xW1 + 16 * DI, xW_bc2, 32 * DI);
    k_combo2<<<dim3((DI * DI) / 256, 2), 256, 0, stream>>>(dtW0, dtW1, xW0, xW1, Wcombo2);

    // encoder
    k_transp<<<dim3(T_LR / 32, 2, B_SZ), 256, 0, stream>>>(x, xt, 64);
    k_conv3_bf<<<dim3(BT / 128, 1), 256, 0, stream>>>(xt, 64, nullptr, 0, W1r,
                                                      nullptr, enc_b1, nullptr, e1t, 128, 1, 0);
    k_conv3_bf<<<dim3(BT / 128, 2), 256, 0, stream>>>(e1t, 128, nullptr, 0, W2r,
                                                      nullptr, enc_b2, t_buf, tb_bf, 256, 1, 0);
    k_rmsnorm<<<BT / 4, 256, 0, stream>>>(t_buf, norm1_w, xn_buf, xn_bf, BT);

    // mamba: both directions folded per dispatch
    for (int b0 = 0; b0 < B_SZ; b0 += Bc) {
        int Tc = Bc * T_LR;
        size_t dxStr = (size_t)Tc * DI;       // ushorts per dir (xcs / dt)
        size_t dbStr = (size_t)Tc * 32;       // floats per dir
        size_t hStr  = (size_t)Bc * CH * DI * DS;
        size_t cStr  = (size_t)Bc * CH * DI;
        unsigned short* xcs2 = (unsigned short*)scratch;
        unsigned short* dt2  = xcs2 + 2 * dxStr;
        float* db2   = (float*)(dt2 + 2 * dxStr);
        float* hS2   = db2 + 2 * dbStr;
        float* csum2 = hS2 + 2 * hStr;
        const float*          xnC  = xn_buf + (size_t)b0 * T_LR * DM;
        const unsigned short* xnbC = xn_bf  + (size_t)b0 * T_LR * DM;
        float*                moC  = mo     + (size_t)b0 * T_LR * DM;
        // fused in_proj(xc) + causal dwconv + silu -> xcs bf16  [both dirs]
        k_inproj_conv2<<<dim3(Tc / 128, DI / 128, 2), 256, 0, stream>>>(
            xnbC, inW_bf2, convW0, convW1, convb0, convb1, xcs2, dxStr);
        // dt = softplus(xcs @ Wcombo^T + dtb) -> bf16  [both dirs]
        k_gemm_bf2<<<dim3(Tc / 128, DI / 128, 2), 256, 0, stream>>>(
            xcs2, dxStr, Wcombo2, (size_t)DI * DI, nullptr, 0, dt2, dxStr,
            dtb0, dtb1, nullptr, 0, DI, DI, DI, DI, 2, 0);
        // db (B,C) = xcs @ xW[16:48]^T -> fp32  [both dirs]
        k_gemm_bf2<<<dim3(Tc / 128, 1, 2), 256, 0, stream>>>(
            xcs2, dxStr, xW_bc2, (size_t)32 * DI, db2, dbStr, nullptr, 0,
            nullptr, nullptr, nullptr, 0, DI, 32, DI, 32, 0, 0);
        // chunked scan; y bf16 in place over xcs  [both dirs]
        k_scan_p1<<<dim3((Bc * CH * DI) / 256, 2), 256, 0, stream>>>(
            dt2, xcs2, db2, Alog0, Alog1, hS2, csum2, dxStr, dbStr, hStr, cStr);
        k_scan_p2<<<dim3((Bc * DI * DS) / 256, 2), 256, 0, stream>>>(
            hS2, csum2, Alog0, Alog1, hStr, cStr);
        k_scan_p3<<<dim3((Bc * CH * DI) / 256, 2), 256, 0, stream>>>(
            dt2, xcs2, db2, Alog0, Alog1, Dp0, Dp1, hS2, dxStr, dbStr, hStr);
        // z GEMM + gate: yg = bf16(y * silu(z)) -> overlays dt buffer  [both dirs]
        k_gemm_bf2<<<dim3(Tc / 128, DI / 128, 2), 256, 0, stream>>>(
            xnbC, 0, inW_bf2 + (size_t)DI * DM, (size_t)1024 * DM,
            nullptr, 0, dt2, dxStr, nullptr, nullptr, xcs2, dxStr,
            DM, DI, DM, DI, 0, 1);
        // out_proj: sequential (dir1 accumulates into dir0's mo)
        k_gemm_bf<<<dim3(Tc / 128, DM / 128), 256, 0, stream>>>(
            dt2, DI, outW_bf2, moC, nullptr, DM, xnC, nullptr, nullptr,
            DI, DM, 0, 0, 0, 0);
        k_gemm_bf<<<dim3(Tc / 128, DM / 128), 256, 0, stream>>>(
            dt2 + dxStr, DI, outW_bf2 + (size_t)DM * DI, moC, nullptr, DM, xnC,
            nullptr, nullptr, DI, DM, 0, 0, 1, 1);
    }

    // combined = rmsnorm(mo) -> comb_bf (xn_buf overlay)
    k_rmsnorm<<<BT / 4, 256, 0, stream>>>(mo, norm2_w, nullptr, comb_bf, BT);
    // convd + bn + silu -> d_bf (mo overlay)
    k_conv3_bf<<<dim3(BT / 128, 2), 256, 0, stream>>>(comb_bf, 256, tb_bf, 256, Wdr,
                                                      alpha_d, beta_d, nullptr, d_bf, 256, 1, 0);
    // sp conv + pixel shuffle -> out
    k_conv3_bf<<<dim3(BT / 128, 1), 256, 0, stream>>>(d_bf, 256, nullptr, 0, Wspr,
                                                      nullptr, sp_b, out, nullptr, 128, 0, 1);
}

// Round 11
// 1624.162 us; speedup vs baseline: 1.3802x; 1.1637x over previous
//
#include <hip/hip_runtime.h>
#include <hip/hip_bf16.h>
#include <math.h>

#define B_SZ 16
#define T_LR 2560
#define BT (B_SZ * T_LR)     // 40960 tokens
#define DM 256               // d_model
#define DI 512               // d_inner
#define DS 16                // d_state
#define DTR 16               // dt_rank
#define CH 128               // scan chunks per sequence
#define CH_LOG2 7
#define CLEN (T_LR / CH)     // 20 steps per chunk

typedef __attribute__((ext_vector_type(8))) short bf16x8;
typedef __attribute__((ext_vector_type(4))) float f32x4;

__device__ __forceinline__ float silu_f(float x) {
    return x / (1.f + __expf(-x));
}
__device__ __forceinline__ unsigned short f2bf(float v) {
    __hip_bfloat16 h = __float2bfloat16(v);
    return *(unsigned short*)&h;
}
__device__ __forceinline__ float bf2f(unsigned short u) {
    union { unsigned int i; float f; } c;
    c.i = (unsigned int)u << 16;
    return c.f;
}
__device__ __forceinline__ int seqrev(int r) {
    int s = r / T_LR, t = r % T_LR;
    return s * T_LR + (T_LR - 1 - t);
}

// ---------------------------------------------------------------------------
// transpose (b,nch,T) f32 -> (b,T,nch) bf16
// ---------------------------------------------------------------------------
__global__ __launch_bounds__(256) void k_transp(const float* __restrict__ in,
                                                unsigned short* __restrict__ outb,
                                                int nch) {
    __shared__ float s[32][33];
    int b = blockIdx.z;
    int t0 = blockIdx.x * 32, c0 = blockIdx.y * 32;
    int tx = threadIdx.x & 31, ty = threadIdx.x >> 5;   // 32 x 8
    #pragma unroll
    for (int j = 0; j < 4; j++) {
        int c = c0 + ty + j * 8;
        s[ty + j * 8][tx] = in[((size_t)b * nch + c) * T_LR + t0 + tx];
    }
    __syncthreads();
    #pragma unroll
    for (int j = 0; j < 4; j++) {
        int t = t0 + ty + j * 8;
        outb[((size_t)b * T_LR + t) * nch + c0 + tx] = f2bf(s[tx][ty + j * 8]);
    }
}

// ---------------------------------------------------------------------------
// weight rearrange: in (N,K,3) f32 -> out [3][N][K] bf16
// ---------------------------------------------------------------------------
__global__ __launch_bounds__(256) void k_wrearr(const float* __restrict__ in,
                                                unsigned short* __restrict__ out,
                                                int N, int K) {
    int i = blockIdx.x * 256 + threadIdx.x;     // n*K + ci
    if (i >= N * K) return;
    int n = i / K, ci = i % K;
    #pragma unroll
    for (int k = 0; k < 3; k++)
        out[((size_t)k * N + n) * K + ci] = f2bf(in[((size_t)n * K + ci) * 3 + k]);
}

// ---------------------------------------------------------------------------
// fold BN into alpha/beta (256 ch): v = alpha*conv + beta
// ---------------------------------------------------------------------------
__global__ __launch_bounds__(256) void k_bnfold(const float* __restrict__ cb,
                                                const float* __restrict__ bng,
                                                const float* __restrict__ bnb,
                                                const float* __restrict__ bnm,
                                                const float* __restrict__ bnv,
                                                float* __restrict__ alpha,
                                                float* __restrict__ beta) {
    int c = threadIdx.x;
    float a = bng[c] * rsqrtf(bnv[c] + 1e-5f);
    alpha[c] = a;
    beta[c] = (cb[c] - bnm[c]) * a + bnb[c];
}

// ---------------------------------------------------------------------------
// dual-dir f32 -> bf16 cast: dst[0:n) = bf(s0), dst[n:2n) = bf(s1)
// ---------------------------------------------------------------------------
__global__ __launch_bounds__(256) void k_cast2(const float* __restrict__ s0,
                                               const float* __restrict__ s1,
                                               unsigned short* __restrict__ d, int n) {
    int i = blockIdx.x * 256 + threadIdx.x;
    if (i < n) { d[i] = f2bf(s0[i]); d[n + i] = f2bf(s1[i]); }
}

// ---------------------------------------------------------------------------
// dual-dir combo weight: Wc[z][n][k] = sum_j dtW_z[n][j] * xW_z[j][k]
// ---------------------------------------------------------------------------
__global__ __launch_bounds__(256) void k_combo2(const float* __restrict__ dtW0,
                                                const float* __restrict__ dtW1,
                                                const float* __restrict__ xW0,
                                                const float* __restrict__ xW1,
                                                unsigned short* __restrict__ Wc) {
    int z = blockIdx.y;
    const float* dtW = z ? dtW1 : dtW0;
    const float* xW  = z ? xW1  : xW0;
    int i = blockIdx.x * 256 + threadIdx.x;   // n*512 + k
    int n = i >> 9, k = i & 511;
    float v = 0.f;
    #pragma unroll
    for (int j = 0; j < 16; j++) v += dtW[n * 16 + j] * xW[j * 512 + k];
    Wc[(size_t)z * DI * DI + i] = f2bf(v);
}

// ---------------------------------------------------------------------------
// implicit-GEMM k=3 "same" conv via MFMA (encoder/decoder convs).
// ---------------------------------------------------------------------------
__global__ __launch_bounds__(256) void k_conv3_bf(const unsigned short* __restrict__ A1, int K1,
                                                  const unsigned short* __restrict__ A2, int K2,
                                                  const unsigned short* __restrict__ W,
                                                  const float* __restrict__ alpha,
                                                  const float* __restrict__ beta,
                                                  float* __restrict__ outf,
                                                  unsigned short* __restrict__ outb,
                                                  int N, int dosilu, int pixsh) {
    int Kt = K1 + K2;
    __shared__ unsigned short As[130][40];
    __shared__ unsigned short Bs[3][128][40];
    int tid = threadIdx.x;
    int wave = tid >> 6, lane = tid & 63;
    int wm = (wave >> 1) * 64, wn = (wave & 1) * 64;
    int m0 = blockIdx.x * 128, n0 = blockIdx.y * 128;
    int b = m0 / T_LR, t0 = m0 % T_LR;
    int q = lane >> 4, ml = lane & 15;
    f32x4 acc[4][4] = {};
    for (int k0 = 0; k0 < Kt; k0 += 32) {
        __syncthreads();
        for (int i = tid; i < 520; i += 256) {
            int row = i >> 2, cq = i & 3;
            int t = t0 - 1 + row;
            uint4 v = make_uint4(0u, 0u, 0u, 0u);
            if (t >= 0 && t < T_LR) {
                int col = k0 + cq * 8;
                const unsigned short* src = (col < K1)
                    ? A1 + (size_t)(b * T_LR + t) * K1 + col
                    : A2 + (size_t)(b * T_LR + t) * K2 + (col - K1);
                v = *(const uint4*)src;
            }
            *(uint4*)&As[row][cq * 8] = v;
        }
        for (int i = tid; i < 1536; i += 256) {
            int tap = i >> 9;
            int r = (i >> 2) & 127;
            int cq = i & 3;
            *(uint4*)&Bs[tap][r][cq * 8] =
                *(const uint4*)(W + ((size_t)tap * N + n0 + r) * Kt + k0 + cq * 8);
        }
        __syncthreads();
        #pragma unroll
        for (int tap = 0; tap < 3; tap++) {
            bf16x8 bfr[4];
            #pragma unroll
            for (int ni = 0; ni < 4; ni++)
                bfr[ni] = *(const bf16x8*)&Bs[tap][wn + ni * 16 + ml][q * 8];
            #pragma unroll
            for (int mi = 0; mi < 4; mi++) {
                bf16x8 af = *(const bf16x8*)&As[wm + mi * 16 + ml + tap][q * 8];
                #pragma unroll
                for (int ni = 0; ni < 4; ni++)
                    acc[mi][ni] = __builtin_amdgcn_mfma_f32_16x16x32_bf16(af, bfr[ni], acc[mi][ni], 0, 0, 0);
            }
        }
    }
    #pragma unroll
    for (int mi = 0; mi < 4; mi++) {
        #pragma unroll
        for (int r = 0; r < 4; r++) {
            int mr = m0 + wm + mi * 16 + q * 4 + r;
            int t = mr - b * T_LR;
            #pragma unroll
            for (int ni = 0; ni < 4; ni++) {
                int col = n0 + wn + ni * 16 + ml;
                float a = alpha ? alpha[col] : 1.f;
                float v = acc[mi][ni][r] * a + beta[col];
                if (dosilu) v = silu_f(v);
                if (pixsh) {
                    int c2 = col >> 1, rr = col & 1;
                    outf[(((size_t)b * 64 + c2) * T_LR + t) * 2 + rr] = v;
                } else {
                    size_t o = (size_t)mr * N + col;
                    if (outf) outf[o] = v;
                    if (outb) outb[o] = f2bf(v);
                }
            }
        }
    }
}

// ---------------------------------------------------------------------------
// fused in_proj (xc half) + causal depthwise conv k=4 + silu -> xcs bf16.
// ---------------------------------------------------------------------------
__global__ __launch_bounds__(256) void k_inproj_conv(const unsigned short* __restrict__ xn,
                                                     const unsigned short* __restrict__ inW,
                                                     const float* __restrict__ cw,
                                                     const float* __restrict__ cb,
                                                     unsigned short* __restrict__ xcs,
                                                     int arev) {
    __shared__ unsigned short As[128][40];
    __shared__ unsigned short Bs[128][40];
    __shared__ unsigned short Ct[131][136];   // rows: internal t0-3 .. t0+127
    int tid = threadIdx.x;
    int wave = tid >> 6, lane = tid & 63;
    int wm = (wave >> 1) * 64, wn = (wave & 1) * 64;
    int m0 = blockIdx.x * 128, n0 = blockIdx.y * 128;
    int b = m0 / T_LR, t0 = m0 % T_LR;
    int sc = tid & 3, sr = tid >> 2;
    int ar0 = m0 + sr, ar1 = m0 + sr + 64;
    if (arev) { ar0 = seqrev(ar0); ar1 = seqrev(ar1); }
    const unsigned short* ap0 = xn + (size_t)ar0 * DM + sc * 8;
    const unsigned short* ap1 = xn + (size_t)ar1 * DM + sc * 8;
    const unsigned short* bp0 = inW + (size_t)(n0 + sr) * DM + sc * 8;
    const unsigned short* bp1 = inW + (size_t)(n0 + sr + 64) * DM + sc * 8;
    f32x4 acc[4][4] = {};
    int q = lane >> 4, ml = lane & 15;
    for (int k0 = 0; k0 < DM; k0 += 32) {
        uint4 a0 = *(const uint4*)(ap0 + k0);
        uint4 a1 = *(const uint4*)(ap1 + k0);
        uint4 b0 = *(const uint4*)(bp0 + k0);
        uint4 b1 = *(const uint4*)(bp1 + k0);
        __syncthreads();
        *(uint4*)&As[sr][sc * 8]      = a0;
        *(uint4*)&As[sr + 64][sc * 8] = a1;
        *(uint4*)&Bs[sr][sc * 8]      = b0;
        *(uint4*)&Bs[sr + 64][sc * 8] = b1;
        __syncthreads();
        bf16x8 af[4], bfr[4];
        #pragma unroll
        for (int mi = 0; mi < 4; mi++)
            af[mi] = *(const bf16x8*)&As[wm + mi * 16 + ml][q * 8];
        #pragma unroll
        for (int ni = 0; ni < 4; ni++)
            bfr[ni] = *(const bf16x8*)&Bs[wn + ni * 16 + ml][q * 8];
        #pragma unroll
        for (int mi = 0; mi < 4; mi++)
            #pragma unroll
            for (int ni = 0; ni < 4; ni++)
                acc[mi][ni] = __builtin_amdgcn_mfma_f32_16x16x32_bf16(af[mi], bfr[ni], acc[mi][ni], 0, 0, 0);
    }
    // main tile -> Ct rows 3..130
    #pragma unroll
    for (int mi = 0; mi < 4; mi++)
        #pragma unroll
        for (int r = 0; r < 4; r++)
            #pragma unroll
            for (int ni = 0; ni < 4; ni++)
                Ct[3 + wm + mi * 16 + q * 4 + r][wn + ni * 16 + ml] = f2bf(acc[mi][ni][r]);
    // halo rows 0..2 via direct dot — 384 items on 256 threads
    for (int i = tid; i < 384; i += 256) {
        int hr = i >> 7, c = i & 127;
        int tr = t0 - 3 + hr;
        float v = 0.f;
        if (tr >= 0) {
            int src = b * T_LR + (arev ? (T_LR - 1 - tr) : tr);
            const unsigned short* xr = xn + (size_t)src * DM;
            const unsigned short* wr = inW + (size_t)(n0 + c) * DM;
            for (int k = 0; k < DM; k += 8) {
                uint4 xa = *(const uint4*)(xr + k);
                uint4 wa = *(const uint4*)(wr + k);
                const unsigned short* xs = (const unsigned short*)&xa;
                const unsigned short* wsp = (const unsigned short*)&wa;
                #pragma unroll
                for (int j = 0; j < 8; j++) v += bf2f(xs[j]) * bf2f(wsp[j]);
            }
        }
        Ct[hr][c] = f2bf(v);
    }
    __syncthreads();
    // causal conv k=4 + silu, write xcs bf16
    int col = tid & 127;
    int d = n0 + col;
    float w0 = cw[d * 4 + 0], w1 = cw[d * 4 + 1], w2 = cw[d * 4 + 2], w3 = cw[d * 4 + 3];
    float bi = cb[d];
    int rbase = tid >> 7;
    for (int j = 0; j < 64; j++) {
        int row = rbase + 2 * j;
        float v = bi + bf2f(Ct[row][col]) * w0 + bf2f(Ct[row + 1][col]) * w1
                     + bf2f(Ct[row + 2][col]) * w2 + bf2f(Ct[row + 3][col]) * w3;
        xcs[(size_t)(m0 + row) * DI + d] = f2bf(silu_f(v));
    }
}

// ---------------------------------------------------------------------------
// rmsnorm over last dim (256). One wave per token. fp32 and/or bf16 out.
// ---------------------------------------------------------------------------
__global__ __launch_bounds__(256) void k_rmsnorm(const float* __restrict__ in1,
                                                 const float* __restrict__ w,
                                                 float* __restrict__ out,
                                                 unsigned short* __restrict__ out_bf,
                                                 int ntok) {
    int tok = (blockIdx.x * 256 + threadIdx.x) >> 6;
    int lane = threadIdx.x & 63;
    if (tok >= ntok) return;
    float4 v = ((const float4*)(in1 + (size_t)tok * DM))[lane];
    float ss = v.x * v.x + v.y * v.y + v.z * v.z + v.w * v.w;
    #pragma unroll
    for (int off = 32; off > 0; off >>= 1) ss += __shfl_xor(ss, off);
    float sc = rsqrtf(ss * (1.f / 256.f) + 1e-6f);
    float4 wv = ((const float4*)w)[lane];
    float4 o;
    o.x = v.x * sc * wv.x; o.y = v.y * sc * wv.y;
    o.z = v.z * sc * wv.z; o.w = v.w * sc * wv.w;
    if (out) ((float4*)(out + (size_t)tok * DM))[lane] = o;
    if (out_bf) {
        ushort4 ob;
        ob.x = f2bf(o.x); ob.y = f2bf(o.y); ob.z = f2bf(o.z); ob.w = f2bf(o.w);
        ((ushort4*)(out_bf + (size_t)tok * DM))[lane] = ob;
    }
}

// ---------------------------------------------------------------------------
// bf16 MFMA GEMM, swiss-army epilogue (round-8 form).
// ---------------------------------------------------------------------------
__global__ __launch_bounds__(256) void k_gemm_bf(const unsigned short* __restrict__ A, int lda,
                                                 const unsigned short* __restrict__ Bw,
                                                 float* Cf, unsigned short* Cb, int ldc,
                                                 const float* __restrict__ res,
                                                 const float* __restrict__ bias,
                                                 const unsigned short* __restrict__ gate,
                                                 int K, int Nout, int act,
                                                 int arev, int crev, int accum) {
    __shared__ unsigned short As[128][40];
    __shared__ unsigned short Bs[128][40];
    int tid = threadIdx.x;
    int wave = tid >> 6, lane = tid & 63;
    int wm = (wave >> 1) * 64, wn = (wave & 1) * 64;
    int m0 = blockIdx.x * 128, n0 = blockIdx.y * 128;
    int sc = tid & 3, sr = tid >> 2;
    int ar0 = m0 + sr, ar1 = m0 + sr + 64;
    if (arev) { ar0 = seqrev(ar0); ar1 = seqrev(ar1); }
    const unsigned short* ap0 = A + (size_t)ar0 * lda + sc * 8;
    const unsigned short* ap1 = A + (size_t)ar1 * lda + sc * 8;
    bool bv0 = (n0 + sr) < Nout;
    bool bv1 = (n0 + sr + 64) < Nout;
    const unsigned short* bp0 = Bw + (size_t)(n0 + sr) * K + sc * 8;
    const unsigned short* bp1 = Bw + (size_t)(n0 + sr + 64) * K + sc * 8;
    f32x4 acc[4][4] = {};
    int q = lane >> 4, ml = lane & 15;
    for (int k0 = 0; k0 < K; k0 += 32) {
        uint4 a0 = *(const uint4*)(ap0 + k0);
        uint4 a1 = *(const uint4*)(ap1 + k0);
        uint4 b0 = make_uint4(0u, 0u, 0u, 0u), b1 = make_uint4(0u, 0u, 0u, 0u);
        if (bv0) b0 = *(const uint4*)(bp0 + k0);
        if (bv1) b1 = *(const uint4*)(bp1 + k0);
        __syncthreads();
        *(uint4*)&As[sr][sc * 8]      = a0;
        *(uint4*)&As[sr + 64][sc * 8] = a1;
        *(uint4*)&Bs[sr][sc * 8]      = b0;
        *(uint4*)&Bs[sr + 64][sc * 8] = b1;
        __syncthreads();
        bf16x8 af[4], bfr[4];
        #pragma unroll
        for (int mi = 0; mi < 4; mi++)
            af[mi] = *(const bf16x8*)&As[wm + mi * 16 + ml][q * 8];
        #pragma unroll
        for (int ni = 0; ni < 4; ni++)
            bfr[ni] = *(const bf16x8*)&Bs[wn + ni * 16 + ml][q * 8];
        #pragma unroll
        for (int mi = 0; mi < 4; mi++)
            #pragma unroll
            for (int ni = 0; ni < 4; ni++)
                acc[mi][ni] = __builtin_amdgcn_mfma_f32_16x16x32_bf16(af[mi], bfr[ni], acc[mi][ni], 0, 0, 0);
    }
    #pragma unroll
    for (int mi = 0; mi < 4; mi++) {
        #pragma unroll
        for (int r = 0; r < 4; r++) {
            int mr = m0 + wm + mi * 16 + q * 4 + r;
            int orow = crev ? seqrev(mr) : mr;
            #pragma unroll
            for (int ni = 0; ni < 4; ni++) {
                int col = n0 + wn + ni * 16 + ml;
                if (col < Nout) {
                    float v = acc[mi][ni][r];
                    if (bias) v += bias[col];
                    if (act == 2) v = (v > 20.f) ? v : log1pf(__expf(v));
                    if (gate) v = silu_f(v) * bf2f(gate[(size_t)mr * ldc + col]);
                    if (res) v += res[(size_t)orow * ldc + col];
                    if (accum) v += Cf[(size_t)orow * ldc + col];
                    if (Cf) Cf[(size_t)orow * ldc + col] = v;
                    if (Cb) Cb[(size_t)orow * ldc + col] = f2bf(v);
                }
            }
        }
    }
}

// ---------------------------------------------------------------------------
// scan phase 1: per (bl, chunk, d) thread. Chunk-local scan from h=0.
// dt, x bf16 (stride DI); db fp32 (stride 32: B=0..16, C=16..32)
// ---------------------------------------------------------------------------
__global__ __launch_bounds__(256) void k_scan_p1(const unsigned short* __restrict__ dt,
                                                 const unsigned short* __restrict__ x,
                                                 const float* __restrict__ db,
                                                 const float* __restrict__ Alog,
                                                 float* __restrict__ hS,
                                                 float* __restrict__ csum) {
    int gid = blockIdx.x * 256 + threadIdx.x;   // (bl*CH + c)*DI + d
    int d = gid & (DI - 1);
    int bcix = gid >> 9;
    int c = bcix & (CH - 1);
    int bl = bcix >> CH_LOG2;
    float A[DS], h[DS];
    #pragma unroll
    for (int n = 0; n < DS; n++) { A[n] = -__expf(Alog[d * DS + n]); h[n] = 0.f; }
    int tbase = c * CLEN;
    const unsigned short* dtp = dt + ((size_t)bl * T_LR + tbase) * DI + d;
    const unsigned short* xp  = x  + ((size_t)bl * T_LR + tbase) * DI + d;
    const float* bcp = db + ((size_t)bl * T_LR + tbase) * 32;
    float S = 0.f;
    for (int t = 0; t < CLEN; t++) {
        float dtv = bf2f(dtp[(size_t)t * DI]);
        float xv  = bf2f(xp[(size_t)t * DI]);
        float dtx = dtv * xv;
        const float* bc = bcp + (size_t)t * 32;
        S += dtv;
        #pragma unroll
        for (int n = 0; n < DS; n++)
            h[n] = __expf(dtv * A[n]) * h[n] + dtx * bc[n];
    }
    float* hp = hS + (size_t)gid * DS;
    #pragma unroll
    for (int n = 0; n < DS; n++) hp[n] = h[n];
    csum[gid] = S;
}

// ---------------------------------------------------------------------------
// scan phase 2: per (bl, d, n) thread; sequential over CH chunks, in place.
// ---------------------------------------------------------------------------
__global__ __launch_bounds__(256) void k_scan_p2(float* __restrict__ hS,
                                                 const float* __restrict__ csum,
                                                 const float* __restrict__ Alog) {
    int gid = blockIdx.x * 256 + threadIdx.x;   // (bl*DI + d)*DS + n
    int n = gid & (DS - 1);
    int d = (gid >> 4) & (DI - 1);
    int bl = gid >> 13;
    float An = -__expf(Alog[d * DS + n]);
    float hs = 0.f;
    for (int c = 0; c < CH; c++) {
        size_t base = ((size_t)(bl * CH + c) * DI + d);
        float he = hS[base * DS + n];
        float S  = csum[base];
        hS[base * DS + n] = hs;
        hs = __expf(An * S) * hs + he;
    }
}

// ---------------------------------------------------------------------------
// scan phase 3: corrected chunk-start state; y written bf16 in place over x.
// ---------------------------------------------------------------------------
__global__ __launch_bounds__(256) void k_scan_p3(const unsigned short* __restrict__ dt,
                                                 unsigned short* x,
                                                 const float* __restrict__ db,
                                                 const float* __restrict__ Alog,
                                                 const float* __restrict__ Dp,
                                                 const float* __restrict__ hS) {
    int gid = blockIdx.x * 256 + threadIdx.x;   // (bl*CH + c)*DI + d
    int d = gid & (DI - 1);
    int bcix = gid >> 9;
    int c = bcix & (CH - 1);
    int bl = bcix >> CH_LOG2;
    float A[DS], h[DS];
    const float* hp = hS + (size_t)gid * DS;
    #pragma unroll
    for (int n = 0; n < DS; n++) { A[n] = -__expf(Alog[d * DS + n]); h[n] = hp[n]; }
    float Dd = Dp[d];
    int tbase = c * CLEN;
    const unsigned short* dtp = dt + ((size_t)bl * T_LR + tbase) * DI + d;
    unsigned short* xp = x + ((size_t)bl * T_LR + tbase) * DI + d;
    const float* bcp = db + ((size_t)bl * T_LR + tbase) * 32;
    for (int t = 0; t < CLEN; t++) {
        float dtv = bf2f(dtp[(size_t)t * DI]);
        float xv  = bf2f(xp[(size_t)t * DI]);
        float dtx = dtv * xv;
        const float* bc = bcp + (size_t)t * 32;
        float acc = 0.f;
        #pragma unroll
        for (int n = 0; n < DS; n++) {
            h[n] = __expf(dtv * A[n]) * h[n] + dtx * bc[n];
            acc += h[n] * bc[16 + n];
        }
        xp[(size_t)t * DI] = f2bf(acc + xv * Dd);
    }
}

// ---------------------------------------------------------------------------
extern "C" void kernel_launch(void* const* d_in, const int* in_sizes, int n_in,
                              void* d_out, int out_size, void* d_ws, size_t ws_size,
                              hipStream_t stream) {
    const float* x       = (const float*)d_in[0];
    const float* enc_w1  = (const float*)d_in[1];
    const float* enc_b1  = (const float*)d_in[2];
    const float* enc_w2  = (const float*)d_in[3];
    const float* enc_b2  = (const float*)d_in[4];
    const float* norm1_w = (const float*)d_in[5];
    const float* norm2_w = (const float*)d_in[6];
    const float* convd_w = (const float*)d_in[25];
    const float* convd_b = (const float*)d_in[26];
    const float* bn_g    = (const float*)d_in[27];
    const float* bn_b    = (const float*)d_in[28];
    const float* bn_mean = (const float*)d_in[29];
    const float* bn_var  = (const float*)d_in[30];
    const float* sp_w    = (const float*)d_in[31];
    const float* sp_b    = (const float*)d_in[32];
    float* out = (float*)d_out;

    const float* inW0   = (const float*)d_in[7];
    const float* xW0    = (const float*)d_in[10];
    const float* dtW0   = (const float*)d_in[11];
    const float* outW0  = (const float*)d_in[15];
    const float* inW1   = (const float*)d_in[16];
    const float* xW1    = (const float*)d_in[19];
    const float* dtW1   = (const float*)d_in[20];
    const float* outW1  = (const float*)d_in[24];

    // ---- workspace layout (float slots) ----
    float* ws = (float*)d_ws;
    size_t availf = ws_size / sizeof(float);
    size_t o = 0;
    float* t_buf  = ws + o; o += (size_t)BT * DM;
    float* xn_buf = ws + o; o += (size_t)BT * DM;       // later: comb_bf overlay
    float* mo     = ws + o; o += (size_t)BT * DM;       // early: xt/e1t; late: d_bf overlay
    unsigned short* xn_bf = (unsigned short*)(ws + o); o += (size_t)BT * DM / 2;
    unsigned short* tb_bf = (unsigned short*)(ws + o); o += (size_t)BT * DM / 2;
    unsigned short* inW_bf2  = (unsigned short*)(ws + o); o += (size_t)1024 * DM;   // 2 dirs
    unsigned short* outW_bf2 = (unsigned short*)(ws + o); o += (size_t)DM * DI;     // 2 dirs
    unsigned short* Wcombo2  = (unsigned short*)(ws + o); o += (size_t)DI * DI;     // 2 dirs
    unsigned short* xW_bc2   = (unsigned short*)(ws + o); o += (size_t)32 * DI;     // 2 dirs
    unsigned short* W1r  = (unsigned short*)(ws + o); o += (3 * 128 * 64) / 2;
    unsigned short* W2r  = (unsigned short*)(ws + o); o += (3 * 256 * 128) / 2;
    unsigned short* Wdr  = (unsigned short*)(ws + o); o += (3 * 256 * 512) / 2;
    unsigned short* Wspr = (unsigned short*)(ws + o); o += (3 * 128 * 256) / 2;
    float* alpha_d = ws + o; o += 256;
    float* beta_d  = ws + o; o += 256;
    size_t persist = o;
    float* scratch = ws + persist;
    size_t scratch_avail = (availf > persist) ? (availf - persist) : 0;
    // per-batch scratch (float slots): xcs bf16 + dt bf16 + db f32 + hS + csum
    size_t per_b = (size_t)T_LR * DI / 2 * 2 + (size_t)T_LR * 32
                 + (size_t)CH * DI * (DS + 1);
    int Bc = 16;
    while (Bc > 1 && (size_t)Bc * per_b > scratch_avail) Bc >>= 1;

    // encoder temporaries overlay mo (dead until out_proj accumulation)
    unsigned short* xt  = (unsigned short*)mo;                         // (b,T,64) bf16
    unsigned short* e1t = (unsigned short*)(mo + (size_t)BT * 64 / 2); // (b,T,128) bf16
    unsigned short* comb_bf = (unsigned short*)xn_buf;   // overlay after xn dead
    unsigned short* d_bf = (unsigned short*)mo;          // overlay after mo dead

    // weight prep (both directions up front)
    k_wrearr<<<(128 * 64 + 255) / 256, 256, 0, stream>>>(enc_w1, W1r, 128, 64);
    k_wrearr<<<(256 * 128 + 255) / 256, 256, 0, stream>>>(enc_w2, W2r, 256, 128);
    k_wrearr<<<(256 * 512 + 255) / 256, 256, 0, stream>>>(convd_w, Wdr, 256, 512);
    k_wrearr<<<(128 * 256 + 255) / 256, 256, 0, stream>>>(sp_w, Wspr, 128, 256);
    k_bnfold<<<1, 256, 0, stream>>>(convd_b, bn_g, bn_b, bn_mean, bn_var, alpha_d, beta_d);
    k_cast2<<<(1024 * DM + 255) / 256, 256, 0, stream>>>(inW0, inW1, inW_bf2, 1024 * DM);
    k_cast2<<<(DM * DI + 255) / 256, 256, 0, stream>>>(outW0, outW1, outW_bf2, DM * DI);
    k_cast2<<<(32 * DI + 255) / 256, 256, 0, stream>>>(xW0 + 16 * DI, xW1 + 16 * DI, xW_bc2, 32 * DI);
    k_combo2<<<dim3((DI * DI) / 256, 2), 256, 0, stream>>>(dtW0, dtW1, xW0, xW1, Wcombo2);

    // encoder
    k_transp<<<dim3(T_LR / 32, 2, B_SZ), 256, 0, stream>>>(x, xt, 64);
    k_conv3_bf<<<dim3(BT / 128, 1), 256, 0, stream>>>(xt, 64, nullptr, 0, W1r,
                                                      nullptr, enc_b1, nullptr, e1t, 128, 1, 0);
    k_conv3_bf<<<dim3(BT / 128, 2), 256, 0, stream>>>(e1t, 128, nullptr, 0, W2r,
                                                      nullptr, enc_b2, t_buf, tb_bf, 256, 1, 0);
    k_rmsnorm<<<BT / 4, 256, 0, stream>>>(t_buf, norm1_w, xn_buf, xn_bf, BT);

    for (int dir = 0; dir < 2; dir++) {
        const float* convW = (const float*)d_in[8 + 9 * dir];
        const float* convb = (const float*)d_in[9 + 9 * dir];
        const float* dtb   = (const float*)d_in[12 + 9 * dir];
        const float* Alog  = (const float*)d_in[13 + 9 * dir];
        const float* Dp    = (const float*)d_in[14 + 9 * dir];
        const unsigned short* inW_d  = inW_bf2 + (size_t)dir * 1024 * DM;
        const unsigned short* outW_d = outW_bf2 + (size_t)dir * DM * DI;
        const unsigned short* Wc_d   = Wcombo2 + (size_t)dir * DI * DI;
        const unsigned short* xWbc_d = xW_bc2 + (size_t)dir * 32 * DI;
        int rev = dir;
        for (int b0 = 0; b0 < B_SZ; b0 += Bc) {
            int Tc = Bc * T_LR;
            unsigned short* xcs = (unsigned short*)scratch;                       // bf16, later y
            unsigned short* dtb16 = xcs + (size_t)Tc * DI;                        // bf16, later yg
            float* db   = (float*)(dtb16 + (size_t)Tc * DI);
            float* hS   = db + (size_t)Tc * 32;
            float* csum = hS + (size_t)Bc * CH * DI * DS;
            const float*          xnC  = xn_buf + (size_t)b0 * T_LR * DM;
            const unsigned short* xnbC = xn_bf  + (size_t)b0 * T_LR * DM;
            float*                moC  = mo     + (size_t)b0 * T_LR * DM;
            // fused in_proj(xc) + causal dwconv + silu -> xcs bf16
            k_inproj_conv<<<dim3(Tc / 128, DI / 128), 256, 0, stream>>>(
                xnbC, inW_d, convW, convb, xcs, rev);
            // dt = softplus(xcs @ Wcombo^T + dtb) -> bf16
            k_gemm_bf<<<dim3(Tc / 128, DI / 128), 256, 0, stream>>>(
                xcs, DI, Wc_d, nullptr, dtb16, DI, nullptr, dtb, nullptr,
                DI, DI, 2, 0, 0, 0);
            // db (B,C) = xcs @ xW[16:48]^T -> fp32 (Tc,32)
            k_gemm_bf<<<dim3(Tc / 128, 1), 256, 0, stream>>>(
                xcs, DI, xWbc_d, db, nullptr, 32, nullptr, nullptr, nullptr,
                DI, 32, 0, 0, 0, 0);
            // chunked scan (CH=128, CLEN=20); y bf16 in place over xcs
            k_scan_p1<<<(Bc * CH * DI) / 256, 256, 0, stream>>>(dtb16, xcs, db, Alog, hS, csum);
            k_scan_p2<<<(Bc * DI * DS) / 256, 256, 0, stream>>>(hS, csum, Alog);
            k_scan_p3<<<(Bc * CH * DI) / 256, 256, 0, stream>>>(dtb16, xcs, db, Alog, Dp, hS);
            // z GEMM + gate: yg = bf16(y * silu(z)) -> overlays dt buffer
            k_gemm_bf<<<dim3(Tc / 128, DI / 128), 256, 0, stream>>>(
                xnbC, DM, inW_d + (size_t)DI * DM, nullptr, dtb16, DI,
                nullptr, nullptr, xcs, DM, DI, 0, rev, 0, 0);
            // mo (+)= yg @ outW^T + xn
            k_gemm_bf<<<dim3(Tc / 128, DM / 128), 256, 0, stream>>>(
                dtb16, DI, outW_d, moC, nullptr, DM, xnC, nullptr, nullptr,
                DI, DM, 0, 0, rev, dir);
        }
    }

    // combined = rmsnorm(mo) -> comb_bf (xn_buf overlay)
    k_rmsnorm<<<BT / 4, 256, 0, stream>>>(mo, norm2_w, nullptr, comb_bf, BT);
    // convd + bn + silu -> d_bf (mo overlay)
    k_conv3_bf<<<dim3(BT / 128, 2), 256, 0, stream>>>(comb_bf, 256, tb_bf, 256, Wdr,
                                                      alpha_d, beta_d, nullptr, d_bf, 256, 1, 0);
    // sp conv + pixel shuffle -> out
    k_conv3_bf<<<dim3(BT / 128, 1), 256, 0, stream>>>(d_bf, 256, nullptr, 0, Wspr,
                                                      nullptr, sp_b, out, nullptr, 128, 0, 1);
}

// Round 12
// 1576.031 us; speedup vs baseline: 1.4223x; 1.0305x over previous
//
#include <hip/hip_runtime.h>
#include <hip/hip_bf16.h>
#include <math.h>

#define B_SZ 16
#define T_LR 2560
#define BT (B_SZ * T_LR)     // 40960 tokens
#define DM 256               // d_model
#define DI 512               // d_inner
#define DS 16                // d_state
#define DTR 16               // dt_rank
#define CH 128               // scan chunks per sequence
#define CH_LOG2 7
#define CLEN (T_LR / CH)     // 20 steps per chunk

typedef __attribute__((ext_vector_type(8))) short bf16x8;
typedef __attribute__((ext_vector_type(4))) float f32x4;

__device__ __forceinline__ float silu_f(float x) {
    return x / (1.f + __expf(-x));
}
__device__ __forceinline__ unsigned short f2bf(float v) {
    __hip_bfloat16 h = __float2bfloat16(v);
    return *(unsigned short*)&h;
}
__device__ __forceinline__ float bf2f(unsigned short u) {
    union { unsigned int i; float f; } c;
    c.i = (unsigned int)u << 16;
    return c.f;
}
__device__ __forceinline__ int seqrev(int r) {
    int s = r / T_LR, t = r % T_LR;
    return s * T_LR + (T_LR - 1 - t);
}

// ---------------------------------------------------------------------------
// mega prep kernel: all weight transforms + input transpose, one dispatch.
// segments by blockIdx.x:
//  [0,32)    W1r rearr      [32,160)  W2r rearr     [160,672) Wdr rearr
//  [672,800) Wspr rearr     [800,801) bnfold        [801,1825) inW cast x2
//  [1825,2337) outW cast x2 [2337,2401) xW_bc cast  [2401,4449) combo x2
//  [4449,7009) x transpose -> xt bf16
// ---------------------------------------------------------------------------
__global__ __launch_bounds__(256) void k_prep(
    const float* __restrict__ enc_w1, const float* __restrict__ enc_w2,
    const float* __restrict__ convd_w, const float* __restrict__ sp_w,
    const float* __restrict__ convd_b, const float* __restrict__ bn_g,
    const float* __restrict__ bn_b, const float* __restrict__ bn_mean,
    const float* __restrict__ bn_var,
    const float* __restrict__ inW0, const float* __restrict__ inW1,
    const float* __restrict__ outW0, const float* __restrict__ outW1,
    const float* __restrict__ xW0, const float* __restrict__ xW1,
    const float* __restrict__ dtW0, const float* __restrict__ dtW1,
    const float* __restrict__ x,
    unsigned short* __restrict__ W1r, unsigned short* __restrict__ W2r,
    unsigned short* __restrict__ Wdr, unsigned short* __restrict__ Wspr,
    float* __restrict__ alpha, float* __restrict__ beta,
    unsigned short* __restrict__ inW_bf2, unsigned short* __restrict__ outW_bf2,
    unsigned short* __restrict__ xW_bc2, unsigned short* __restrict__ Wcombo2,
    unsigned short* __restrict__ xt)
{
    __shared__ float ts[32][33];
    int blk = blockIdx.x;
    int tid = threadIdx.x;
    if (blk < 32) {                         // W1r: (128,64,3) -> [3][128][64]
        int i = blk * 256 + tid;
        int n = i / 64, ci = i % 64;
        #pragma unroll
        for (int k = 0; k < 3; k++)
            W1r[((size_t)k * 128 + n) * 64 + ci] = f2bf(enc_w1[((size_t)n * 64 + ci) * 3 + k]);
    } else if (blk < 160) {                 // W2r: (256,128,3)
        int i = (blk - 32) * 256 + tid;
        int n = i / 128, ci = i % 128;
        #pragma unroll
        for (int k = 0; k < 3; k++)
            W2r[((size_t)k * 256 + n) * 128 + ci] = f2bf(enc_w2[((size_t)n * 128 + ci) * 3 + k]);
    } else if (blk < 672) {                 // Wdr: (256,512,3)
        int i = (blk - 160) * 256 + tid;
        int n = i / 512, ci = i % 512;
        #pragma unroll
        for (int k = 0; k < 3; k++)
            Wdr[((size_t)k * 256 + n) * 512 + ci] = f2bf(convd_w[((size_t)n * 512 + ci) * 3 + k]);
    } else if (blk < 800) {                 // Wspr: (128,256,3)
        int i = (blk - 672) * 256 + tid;
        int n = i / 256, ci = i % 256;
        #pragma unroll
        for (int k = 0; k < 3; k++)
            Wspr[((size_t)k * 128 + n) * 256 + ci] = f2bf(sp_w[((size_t)n * 256 + ci) * 3 + k]);
    } else if (blk < 801) {                 // bnfold
        int c = tid;
        float a = bn_g[c] * rsqrtf(bn_var[c] + 1e-5f);
        alpha[c] = a;
        beta[c] = (convd_b[c] - bn_mean[c]) * a + bn_b[c];
    } else if (blk < 1825) {                // inW cast, both dirs (262144 each)
        int i = (blk - 801) * 256 + tid;
        inW_bf2[i] = f2bf(inW0[i]);
        inW_bf2[262144 + i] = f2bf(inW1[i]);
    } else if (blk < 2337) {                // outW cast (131072 each)
        int i = (blk - 1825) * 256 + tid;
        outW_bf2[i] = f2bf(outW0[i]);
        outW_bf2[131072 + i] = f2bf(outW1[i]);
    } else if (blk < 2401) {                // xW[16:48] cast (16384 each)
        int i = (blk - 2337) * 256 + tid;
        xW_bc2[i] = f2bf(xW0[16 * DI + i]);
        xW_bc2[16384 + i] = f2bf(xW1[16 * DI + i]);
    } else if (blk < 4449) {                // combo: Wc[z][n][k] = dtW_z @ xW_z[0:16]
        int ii = (blk - 2401) * 256 + tid;
        int z = ii >> 18;
        int i = ii & 262143;
        const float* dtW = z ? dtW1 : dtW0;
        const float* xW  = z ? xW1  : xW0;
        int n = i >> 9, k = i & 511;
        float v = 0.f;
        #pragma unroll
        for (int j = 0; j < 16; j++) v += dtW[n * 16 + j] * xW[j * 512 + k];
        Wcombo2[(size_t)z * DI * DI + i] = f2bf(v);
    } else {                                // transpose x (b,64,T) f32 -> xt (b,T,64) bf16
        int idx = blk - 4449;               // b(16) x c0(2) x t0(80)
        int t0 = (idx % 80) * 32;
        int c0 = ((idx / 80) & 1) * 32;
        int b = idx / 160;
        int tx = tid & 31, ty = tid >> 5;
        #pragma unroll
        for (int j = 0; j < 4; j++) {
            int c = c0 + ty + j * 8;
            ts[ty + j * 8][tx] = x[((size_t)b * 64 + c) * T_LR + t0 + tx];
        }
        __syncthreads();
        #pragma unroll
        for (int j = 0; j < 4; j++) {
            int t = t0 + ty + j * 8;
            xt[((size_t)b * T_LR + t) * 64 + c0 + tx] = f2bf(ts[tx][ty + j * 8]);
        }
    }
}

// ---------------------------------------------------------------------------
// implicit-GEMM k=3 "same" conv via MFMA (encoder/decoder convs).
// ---------------------------------------------------------------------------
__global__ __launch_bounds__(256) void k_conv3_bf(const unsigned short* __restrict__ A1, int K1,
                                                  const unsigned short* __restrict__ A2, int K2,
                                                  const unsigned short* __restrict__ W,
                                                  const float* __restrict__ alpha,
                                                  const float* __restrict__ beta,
                                                  float* __restrict__ outf,
                                                  unsigned short* __restrict__ outb,
                                                  int N, int dosilu, int pixsh) {
    int Kt = K1 + K2;
    __shared__ unsigned short As[130][40];
    __shared__ unsigned short Bs[3][128][40];
    int tid = threadIdx.x;
    int wave = tid >> 6, lane = tid & 63;
    int wm = (wave >> 1) * 64, wn = (wave & 1) * 64;
    int m0 = blockIdx.x * 128, n0 = blockIdx.y * 128;
    int b = m0 / T_LR, t0 = m0 % T_LR;
    int q = lane >> 4, ml = lane & 15;
    f32x4 acc[4][4] = {};
    for (int k0 = 0; k0 < Kt; k0 += 32) {
        __syncthreads();
        for (int i = tid; i < 520; i += 256) {
            int row = i >> 2, cq = i & 3;
            int t = t0 - 1 + row;
            uint4 v = make_uint4(0u, 0u, 0u, 0u);
            if (t >= 0 && t < T_LR) {
                int col = k0 + cq * 8;
                const unsigned short* src = (col < K1)
                    ? A1 + (size_t)(b * T_LR + t) * K1 + col
                    : A2 + (size_t)(b * T_LR + t) * K2 + (col - K1);
                v = *(const uint4*)src;
            }
            *(uint4*)&As[row][cq * 8] = v;
        }
        for (int i = tid; i < 1536; i += 256) {
            int tap = i >> 9;
            int r = (i >> 2) & 127;
            int cq = i & 3;
            *(uint4*)&Bs[tap][r][cq * 8] =
                *(const uint4*)(W + ((size_t)tap * N + n0 + r) * Kt + k0 + cq * 8);
        }
        __syncthreads();
        #pragma unroll
        for (int tap = 0; tap < 3; tap++) {
            bf16x8 bfr[4];
            #pragma unroll
            for (int ni = 0; ni < 4; ni++)
                bfr[ni] = *(const bf16x8*)&Bs[tap][wn + ni * 16 + ml][q * 8];
            #pragma unroll
            for (int mi = 0; mi < 4; mi++) {
                bf16x8 af = *(const bf16x8*)&As[wm + mi * 16 + ml + tap][q * 8];
                #pragma unroll
                for (int ni = 0; ni < 4; ni++)
                    acc[mi][ni] = __builtin_amdgcn_mfma_f32_16x16x32_bf16(af, bfr[ni], acc[mi][ni], 0, 0, 0);
            }
        }
    }
    #pragma unroll
    for (int mi = 0; mi < 4; mi++) {
        #pragma unroll
        for (int r = 0; r < 4; r++) {
            int mr = m0 + wm + mi * 16 + q * 4 + r;
            int t = mr - b * T_LR;
            #pragma unroll
            for (int ni = 0; ni < 4; ni++) {
                int col = n0 + wn + ni * 16 + ml;
                float a = alpha ? alpha[col] : 1.f;
                float v = acc[mi][ni][r] * a + beta[col];
                if (dosilu) v = silu_f(v);
                if (pixsh) {
                    int c2 = col >> 1, rr = col & 1;
                    outf[(((size_t)b * 64 + c2) * T_LR + t) * 2 + rr] = v;
                } else {
                    size_t o = (size_t)mr * N + col;
                    if (outf) outf[o] = v;
                    if (outb) outb[o] = f2bf(v);
                }
            }
        }
    }
}

// ---------------------------------------------------------------------------
// fused in_proj (xc half) + causal depthwise conv k=4 + silu -> xcs bf16.
// ---------------------------------------------------------------------------
__global__ __launch_bounds__(256) void k_inproj_conv(const unsigned short* __restrict__ xn,
                                                     const unsigned short* __restrict__ inW,
                                                     const float* __restrict__ cw,
                                                     const float* __restrict__ cb,
                                                     unsigned short* __restrict__ xcs,
                                                     int arev) {
    __shared__ unsigned short As[128][40];
    __shared__ unsigned short Bs[128][40];
    __shared__ unsigned short Ct[131][136];   // rows: internal t0-3 .. t0+127
    int tid = threadIdx.x;
    int wave = tid >> 6, lane = tid & 63;
    int wm = (wave >> 1) * 64, wn = (wave & 1) * 64;
    int m0 = blockIdx.x * 128, n0 = blockIdx.y * 128;
    int b = m0 / T_LR, t0 = m0 % T_LR;
    int sc = tid & 3, sr = tid >> 2;
    int ar0 = m0 + sr, ar1 = m0 + sr + 64;
    if (arev) { ar0 = seqrev(ar0); ar1 = seqrev(ar1); }
    const unsigned short* ap0 = xn + (size_t)ar0 * DM + sc * 8;
    const unsigned short* ap1 = xn + (size_t)ar1 * DM + sc * 8;
    const unsigned short* bp0 = inW + (size_t)(n0 + sr) * DM + sc * 8;
    const unsigned short* bp1 = inW + (size_t)(n0 + sr + 64) * DM + sc * 8;
    f32x4 acc[4][4] = {};
    int q = lane >> 4, ml = lane & 15;
    for (int k0 = 0; k0 < DM; k0 += 32) {
        uint4 a0 = *(const uint4*)(ap0 + k0);
        uint4 a1 = *(const uint4*)(ap1 + k0);
        uint4 b0 = *(const uint4*)(bp0 + k0);
        uint4 b1 = *(const uint4*)(bp1 + k0);
        __syncthreads();
        *(uint4*)&As[sr][sc * 8]      = a0;
        *(uint4*)&As[sr + 64][sc * 8] = a1;
        *(uint4*)&Bs[sr][sc * 8]      = b0;
        *(uint4*)&Bs[sr + 64][sc * 8] = b1;
        __syncthreads();
        bf16x8 af[4], bfr[4];
        #pragma unroll
        for (int mi = 0; mi < 4; mi++)
            af[mi] = *(const bf16x8*)&As[wm + mi * 16 + ml][q * 8];
        #pragma unroll
        for (int ni = 0; ni < 4; ni++)
            bfr[ni] = *(const bf16x8*)&Bs[wn + ni * 16 + ml][q * 8];
        #pragma unroll
        for (int mi = 0; mi < 4; mi++)
            #pragma unroll
            for (int ni = 0; ni < 4; ni++)
                acc[mi][ni] = __builtin_amdgcn_mfma_f32_16x16x32_bf16(af[mi], bfr[ni], acc[mi][ni], 0, 0, 0);
    }
    // main tile -> Ct rows 3..130
    #pragma unroll
    for (int mi = 0; mi < 4; mi++)
        #pragma unroll
        for (int r = 0; r < 4; r++)
            #pragma unroll
            for (int ni = 0; ni < 4; ni++)
                Ct[3 + wm + mi * 16 + q * 4 + r][wn + ni * 16 + ml] = f2bf(acc[mi][ni][r]);
    // halo rows 0..2 via direct dot — 384 items on 256 threads
    for (int i = tid; i < 384; i += 256) {
        int hr = i >> 7, c = i & 127;
        int tr = t0 - 3 + hr;
        float v = 0.f;
        if (tr >= 0) {
            int src = b * T_LR + (arev ? (T_LR - 1 - tr) : tr);
            const unsigned short* xr = xn + (size_t)src * DM;
            const unsigned short* wr = inW + (size_t)(n0 + c) * DM;
            for (int k = 0; k < DM; k += 8) {
                uint4 xa = *(const uint4*)(xr + k);
                uint4 wa = *(const uint4*)(wr + k);
                const unsigned short* xs = (const unsigned short*)&xa;
                const unsigned short* wsp = (const unsigned short*)&wa;
                #pragma unroll
                for (int j = 0; j < 8; j++) v += bf2f(xs[j]) * bf2f(wsp[j]);
            }
        }
        Ct[hr][c] = f2bf(v);
    }
    __syncthreads();
    // causal conv k=4 + silu, write xcs bf16
    int col = tid & 127;
    int d = n0 + col;
    float w0 = cw[d * 4 + 0], w1 = cw[d * 4 + 1], w2 = cw[d * 4 + 2], w3 = cw[d * 4 + 3];
    float bi = cb[d];
    int rbase = tid >> 7;
    for (int j = 0; j < 64; j++) {
        int row = rbase + 2 * j;
        float v = bi + bf2f(Ct[row][col]) * w0 + bf2f(Ct[row + 1][col]) * w1
                     + bf2f(Ct[row + 2][col]) * w2 + bf2f(Ct[row + 3][col]) * w3;
        xcs[(size_t)(m0 + row) * DI + d] = f2bf(silu_f(v));
    }
}

// ---------------------------------------------------------------------------
// rmsnorm over last dim (256). One wave per token. fp32 and/or bf16 out.
// ---------------------------------------------------------------------------
__global__ __launch_bounds__(256) void k_rmsnorm(const float* __restrict__ in1,
                                                 const float* __restrict__ w,
                                                 float* __restrict__ out,
                                                 unsigned short* __restrict__ out_bf,
                                                 int ntok) {
    int tok = (blockIdx.x * 256 + threadIdx.x) >> 6;
    int lane = threadIdx.x & 63;
    if (tok >= ntok) return;
    float4 v = ((const float4*)(in1 + (size_t)tok * DM))[lane];
    float ss = v.x * v.x + v.y * v.y + v.z * v.z + v.w * v.w;
    #pragma unroll
    for (int off = 32; off > 0; off >>= 1) ss += __shfl_xor(ss, off);
    float sc = rsqrtf(ss * (1.f / 256.f) + 1e-6f);
    float4 wv = ((const float4*)w)[lane];
    float4 o;
    o.x = v.x * sc * wv.x; o.y = v.y * sc * wv.y;
    o.z = v.z * sc * wv.z; o.w = v.w * sc * wv.w;
    if (out) ((float4*)(out + (size_t)tok * DM))[lane] = o;
    if (out_bf) {
        ushort4 ob;
        ob.x = f2bf(o.x); ob.y = f2bf(o.y); ob.z = f2bf(o.z); ob.w = f2bf(o.w);
        ((ushort4*)(out_bf + (size_t)tok * DM))[lane] = ob;
    }
}

// ---------------------------------------------------------------------------
// bf16 MFMA GEMM, swiss-army epilogue (round-8 form; db and out_proj).
// ---------------------------------------------------------------------------
__global__ __launch_bounds__(256) void k_gemm_bf(const unsigned short* __restrict__ A, int lda,
                                                 const unsigned short* __restrict__ Bw,
                                                 float* Cf, unsigned short* Cb, int ldc,
                                                 const float* __restrict__ res,
                                                 const float* __restrict__ bias,
                                                 const unsigned short* __restrict__ gate,
                                                 int K, int Nout, int act,
                                                 int arev, int crev, int accum) {
    __shared__ unsigned short As[128][40];
    __shared__ unsigned short Bs[128][40];
    int tid = threadIdx.x;
    int wave = tid >> 6, lane = tid & 63;
    int wm = (wave >> 1) * 64, wn = (wave & 1) * 64;
    int m0 = blockIdx.x * 128, n0 = blockIdx.y * 128;
    int sc = tid & 3, sr = tid >> 2;
    int ar0 = m0 + sr, ar1 = m0 + sr + 64;
    if (arev) { ar0 = seqrev(ar0); ar1 = seqrev(ar1); }
    const unsigned short* ap0 = A + (size_t)ar0 * lda + sc * 8;
    const unsigned short* ap1 = A + (size_t)ar1 * lda + sc * 8;
    bool bv0 = (n0 + sr) < Nout;
    bool bv1 = (n0 + sr + 64) < Nout;
    const unsigned short* bp0 = Bw + (size_t)(n0 + sr) * K + sc * 8;
    const unsigned short* bp1 = Bw + (size_t)(n0 + sr + 64) * K + sc * 8;
    f32x4 acc[4][4] = {};
    int q = lane >> 4, ml = lane & 15;
    for (int k0 = 0; k0 < K; k0 += 32) {
        uint4 a0 = *(const uint4*)(ap0 + k0);
        uint4 a1 = *(const uint4*)(ap1 + k0);
        uint4 b0 = make_uint4(0u, 0u, 0u, 0u), b1 = make_uint4(0u, 0u, 0u, 0u);
        if (bv0) b0 = *(const uint4*)(bp0 + k0);
        if (bv1) b1 = *(const uint4*)(bp1 + k0);
        __syncthreads();
        *(uint4*)&As[sr][sc * 8]      = a0;
        *(uint4*)&As[sr + 64][sc * 8] = a1;
        *(uint4*)&Bs[sr][sc * 8]      = b0;
        *(uint4*)&Bs[sr + 64][sc * 8] = b1;
        __syncthreads();
        bf16x8 af[4], bfr[4];
        #pragma unroll
        for (int mi = 0; mi < 4; mi++)
            af[mi] = *(const bf16x8*)&As[wm + mi * 16 + ml][q * 8];
        #pragma unroll
        for (int ni = 0; ni < 4; ni++)
            bfr[ni] = *(const bf16x8*)&Bs[wn + ni * 16 + ml][q * 8];
        #pragma unroll
        for (int mi = 0; mi < 4; mi++)
            #pragma unroll
            for (int ni = 0; ni < 4; ni++)
                acc[mi][ni] = __builtin_amdgcn_mfma_f32_16x16x32_bf16(af[mi], bfr[ni], acc[mi][ni], 0, 0, 0);
    }
    #pragma unroll
    for (int mi = 0; mi < 4; mi++) {
        #pragma unroll
        for (int r = 0; r < 4; r++) {
            int mr = m0 + wm + mi * 16 + q * 4 + r;
            int orow = crev ? seqrev(mr) : mr;
            #pragma unroll
            for (int ni = 0; ni < 4; ni++) {
                int col = n0 + wn + ni * 16 + ml;
                if (col < Nout) {
                    float v = acc[mi][ni][r];
                    if (bias) v += bias[col];
                    if (act == 2) v = (v > 20.f) ? v : log1pf(__expf(v));
                    if (gate) v = silu_f(v) * bf2f(gate[(size_t)mr * ldc + col]);
                    if (res) v += res[(size_t)orow * ldc + col];
                    if (accum) v += Cf[(size_t)orow * ldc + col];
                    if (Cf) Cf[(size_t)orow * ldc + col] = v;
                    if (Cb) Cb[(size_t)orow * ldc + col] = f2bf(v);
                }
            }
        }
    }
}

// ---------------------------------------------------------------------------
// bf16-out MFMA GEMM with LDS-transposed vectorized epilogue (dt, z-gate).
// C[M,512](bf16) = op(A[M,K] @ Bw[512,K]^T). op: softplus(v+bias) or
// silu(v)*gate. Full N=512 (no bounds). arev supported.
// ---------------------------------------------------------------------------
__global__ __launch_bounds__(256) void k_gemm_bf_cb(const unsigned short* __restrict__ A, int lda,
                                                    const unsigned short* __restrict__ Bw,
                                                    unsigned short* __restrict__ Cb, int ldc,
                                                    const float* __restrict__ bias,
                                                    const unsigned short* __restrict__ gate,
                                                    int K, int act, int arev) {
    __shared__ __align__(16) unsigned short smem[2 * 128 * 40];   // 20480 B
    unsigned short (*As)[40] = (unsigned short(*)[40])smem;
    unsigned short (*Bs)[40] = (unsigned short(*)[40])(smem + 128 * 40);
    float* sC = (float*)smem;                                     // 32 x 140 f32 (17920 B)
    int tid = threadIdx.x;
    int wave = tid >> 6, lane = tid & 63;
    int wm = (wave >> 1) * 64, wn = (wave & 1) * 64;
    int m0 = blockIdx.x * 128, n0 = blockIdx.y * 128;
    int sc = tid & 3, sr = tid >> 2;
    int ar0 = m0 + sr, ar1 = m0 + sr + 64;
    if (arev) { ar0 = seqrev(ar0); ar1 = seqrev(ar1); }
    const unsigned short* ap0 = A + (size_t)ar0 * lda + sc * 8;
    const unsigned short* ap1 = A + (size_t)ar1 * lda + sc * 8;
    const unsigned short* bp0 = Bw + (size_t)(n0 + sr) * K + sc * 8;
    const unsigned short* bp1 = Bw + (size_t)(n0 + sr + 64) * K + sc * 8;
    f32x4 acc[4][4] = {};
    int q = lane >> 4, ml = lane & 15;
    for (int k0 = 0; k0 < K; k0 += 32) {
        uint4 a0 = *(const uint4*)(ap0 + k0);
        uint4 a1 = *(const uint4*)(ap1 + k0);
        uint4 b0 = *(const uint4*)(bp0 + k0);
        uint4 b1 = *(const uint4*)(bp1 + k0);
        __syncthreads();
        *(uint4*)&As[sr][sc * 8]      = a0;
        *(uint4*)&As[sr + 64][sc * 8] = a1;
        *(uint4*)&Bs[sr][sc * 8]      = b0;
        *(uint4*)&Bs[sr + 64][sc * 8] = b1;
        __syncthreads();
        bf16x8 af[4], bfr[4];
        #pragma unroll
        for (int mi = 0; mi < 4; mi++)
            af[mi] = *(const bf16x8*)&As[wm + mi * 16 + ml][q * 8];
        #pragma unroll
        for (int ni = 0; ni < 4; ni++)
            bfr[ni] = *(const bf16x8*)&Bs[wn + ni * 16 + ml][q * 8];
        #pragma unroll
        for (int mi = 0; mi < 4; mi++)
            #pragma unroll
            for (int ni = 0; ni < 4; ni++)
                acc[mi][ni] = __builtin_amdgcn_mfma_f32_16x16x32_bf16(af[mi], bfr[ni], acc[mi][ni], 0, 0, 0);
    }
    // epilogue: 4 passes of 32 rows through LDS (stride 140 f32)
    #pragma unroll
    for (int p = 0; p < 4; p++) {
        __syncthreads();
        if ((wave >> 1) == (p >> 1)) {
            int mib = (p & 1) * 2;
            #pragma unroll
            for (int m2 = 0; m2 < 2; m2++) {
                int mi = mib + m2;
                int rl = mi * 16 + q * 4 - (p & 1) * 32;
                #pragma unroll
                for (int r = 0; r < 4; r++)
                    #pragma unroll
                    for (int ni = 0; ni < 4; ni++)
                        sC[(rl + r) * 140 + wn + ni * 16 + ml] = acc[mi][ni][r];
            }
        }
        __syncthreads();
        #pragma unroll
        for (int gi = 0; gi < 2; gi++) {
            int g = tid + gi * 256;
            int row = g >> 4;
            int colg = (g & 15) * 8;
            int grow = m0 + p * 32 + row;
            const float* src = sC + row * 140 + colg;
            float4 v0 = *(const float4*)src;
            float4 v1 = *(const float4*)(src + 4);
            float vv[8] = {v0.x, v0.y, v0.z, v0.w, v1.x, v1.y, v1.z, v1.w};
            unsigned short gu[8];
            if (gate)
                *(uint4*)gu = *(const uint4*)(gate + (size_t)grow * ldc + n0 + colg);
            unsigned short o[8];
            #pragma unroll
            for (int jj = 0; jj < 8; jj++) {
                float v = vv[jj];
                if (bias) v += bias[n0 + colg + jj];
                if (act == 2) v = (v > 20.f) ? v : log1pf(__expf(v));
                if (gate) v = silu_f(v) * bf2f(gu[jj]);
                o[jj] = f2bf(v);
            }
            *(uint4*)(Cb + (size_t)grow * ldc + n0 + colg) = *(uint4*)o;
        }
    }
}

// ---------------------------------------------------------------------------
// scan phase 1: per (bl, chunk, d) thread. Chunk-local scan from h=0.
// ---------------------------------------------------------------------------
__global__ __launch_bounds__(256) void k_scan_p1(const unsigned short* __restrict__ dt,
                                                 const unsigned short* __restrict__ x,
                                                 const float* __restrict__ db,
                                                 const float* __restrict__ Alog,
                                                 float* __restrict__ hS,
                                                 float* __restrict__ csum) {
    int gid = blockIdx.x * 256 + threadIdx.x;   // (bl*CH + c)*DI + d
    int d = gid & (DI - 1);
    int bcix = gid >> 9;
    int c = bcix & (CH - 1);
    int bl = bcix >> CH_LOG2;
    float A[DS], h[DS];
    #pragma unroll
    for (int n = 0; n < DS; n++) { A[n] = -__expf(Alog[d * DS + n]); h[n] = 0.f; }
    int tbase = c * CLEN;
    const unsigned short* dtp = dt + ((size_t)bl * T_LR + tbase) * DI + d;
    const unsigned short* xp  = x  + ((size_t)bl * T_LR + tbase) * DI + d;
    const float* bcp = db + ((size_t)bl * T_LR + tbase) * 32;
    float S = 0.f;
    for (int t = 0; t < CLEN; t++) {
        float dtv = bf2f(dtp[(size_t)t * DI]);
        float xv  = bf2f(xp[(size_t)t * DI]);
        float dtx = dtv * xv;
        const float* bc = bcp + (size_t)t * 32;
        S += dtv;
        #pragma unroll
        for (int n = 0; n < DS; n++)
            h[n] = __expf(dtv * A[n]) * h[n] + dtx * bc[n];
    }
    float* hp = hS + (size_t)gid * DS;
    #pragma unroll
    for (int n = 0; n < DS; n++) hp[n] = h[n];
    csum[gid] = S;
}

// ---------------------------------------------------------------------------
// scan phase 2: per (bl, d, n) thread; sequential over CH chunks, in place.
// ---------------------------------------------------------------------------
__global__ __launch_bounds__(256) void k_scan_p2(float* __restrict__ hS,
                                                 const float* __restrict__ csum,
                                                 const float* __restrict__ Alog) {
    int gid = blockIdx.x * 256 + threadIdx.x;   // (bl*DI + d)*DS + n
    int n = gid & (DS - 1);
    int d = (gid >> 4) & (DI - 1);
    int bl = gid >> 13;
    float An = -__expf(Alog[d * DS + n]);
    float hs = 0.f;
    for (int c = 0; c < CH; c++) {
        size_t base = ((size_t)(bl * CH + c) * DI + d);
        float he = hS[base * DS + n];
        float S  = csum[base];
        hS[base * DS + n] = hs;
        hs = __expf(An * S) * hs + he;
    }
}

// ---------------------------------------------------------------------------
// scan phase 3: corrected chunk-start state; y written bf16 in place over x.
// ---------------------------------------------------------------------------
__global__ __launch_bounds__(256) void k_scan_p3(const unsigned short* __restrict__ dt,
                                                 unsigned short* x,
                                                 const float* __restrict__ db,
                                                 const float* __restrict__ Alog,
                                                 const float* __restrict__ Dp,
                                                 const float* __restrict__ hS) {
    int gid = blockIdx.x * 256 + threadIdx.x;   // (bl*CH + c)*DI + d
    int d = gid & (DI - 1);
    int bcix = gid >> 9;
    int c = bcix & (CH - 1);
    int bl = bcix >> CH_LOG2;
    float A[DS], h[DS];
    const float* hp = hS + (size_t)gid * DS;
    #pragma unroll
    for (int n = 0; n < DS; n++) { A[n] = -__expf(Alog[d * DS + n]); h[n] = hp[n]; }
    float Dd = Dp[d];
    int tbase = c * CLEN;
    const unsigned short* dtp = dt + ((size_t)bl * T_LR + tbase) * DI + d;
    unsigned short* xp = x + ((size_t)bl * T_LR + tbase) * DI + d;
    const float* bcp = db + ((size_t)bl * T_LR + tbase) * 32;
    for (int t = 0; t < CLEN; t++) {
        float dtv = bf2f(dtp[(size_t)t * DI]);
        float xv  = bf2f(xp[(size_t)t * DI]);
        float dtx = dtv * xv;
        const float* bc = bcp + (size_t)t * 32;
        float acc = 0.f;
        #pragma unroll
        for (int n = 0; n < DS; n++) {
            h[n] = __expf(dtv * A[n]) * h[n] + dtx * bc[n];
            acc += h[n] * bc[16 + n];
        }
        xp[(size_t)t * DI] = f2bf(acc + xv * Dd);
    }
}

// ---------------------------------------------------------------------------
extern "C" void kernel_launch(void* const* d_in, const int* in_sizes, int n_in,
                              void* d_out, int out_size, void* d_ws, size_t ws_size,
                              hipStream_t stream) {
    const float* x       = (const float*)d_in[0];
    const float* enc_w1  = (const float*)d_in[1];
    const float* enc_b1  = (const float*)d_in[2];
    const float* enc_w2  = (const float*)d_in[3];
    const float* enc_b2  = (const float*)d_in[4];
    const float* norm1_w = (const float*)d_in[5];
    const float* norm2_w = (const float*)d_in[6];
    const float* convd_w = (const float*)d_in[25];
    const float* convd_b = (const float*)d_in[26];
    const float* bn_g    = (const float*)d_in[27];
    const float* bn_b    = (const float*)d_in[28];
    const float* bn_mean = (const float*)d_in[29];
    const float* bn_var  = (const float*)d_in[30];
    const float* sp_w    = (const float*)d_in[31];
    const float* sp_b    = (const float*)d_in[32];
    float* out = (float*)d_out;

    const float* inW0   = (const float*)d_in[7];
    const float* xW0    = (const float*)d_in[10];
    const float* dtW0   = (const float*)d_in[11];
    const float* outW0  = (const float*)d_in[15];
    const float* inW1   = (const float*)d_in[16];
    const float* xW1    = (const float*)d_in[19];
    const float* dtW1   = (const float*)d_in[20];
    const float* outW1  = (const float*)d_in[24];

    // ---- workspace layout (float slots) ----
    float* ws = (float*)d_ws;
    size_t availf = ws_size / sizeof(float);
    size_t o = 0;
    float* t_buf  = ws + o; o += (size_t)BT * DM;
    float* xn_buf = ws + o; o += (size_t)BT * DM;       // later: comb_bf overlay
    float* mo     = ws + o; o += (size_t)BT * DM;       // early: xt/e1t; late: d_bf overlay
    unsigned short* xn_bf = (unsigned short*)(ws + o); o += (size_t)BT * DM / 2;
    unsigned short* tb_bf = (unsigned short*)(ws + o); o += (size_t)BT * DM / 2;
    unsigned short* inW_bf2  = (unsigned short*)(ws + o); o += (size_t)1024 * DM;   // 2 dirs
    unsigned short* outW_bf2 = (unsigned short*)(ws + o); o += (size_t)DM * DI;     // 2 dirs
    unsigned short* Wcombo2  = (unsigned short*)(ws + o); o += (size_t)DI * DI;     // 2 dirs
    unsigned short* xW_bc2   = (unsigned short*)(ws + o); o += (size_t)32 * DI;     // 2 dirs
    unsigned short* W1r  = (unsigned short*)(ws + o); o += (3 * 128 * 64) / 2;
    unsigned short* W2r  = (unsigned short*)(ws + o); o += (3 * 256 * 128) / 2;
    unsigned short* Wdr  = (unsigned short*)(ws + o); o += (3 * 256 * 512) / 2;
    unsigned short* Wspr = (unsigned short*)(ws + o); o += (3 * 128 * 256) / 2;
    float* alpha_d = ws + o; o += 256;
    float* beta_d  = ws + o; o += 256;
    size_t persist = o;
    float* scratch = ws + persist;
    size_t scratch_avail = (availf > persist) ? (availf - persist) : 0;
    // per-batch scratch (float slots): xcs bf16 + dt bf16 + db f32 + hS + csum
    size_t per_b = (size_t)T_LR * DI / 2 * 2 + (size_t)T_LR * 32
                 + (size_t)CH * DI * (DS + 1);
    int Bc = 16;
    while (Bc > 1 && (size_t)Bc * per_b > scratch_avail) Bc >>= 1;

    // encoder temporaries overlay mo (dead until out_proj accumulation)
    unsigned short* xt  = (unsigned short*)mo;                         // (b,T,64) bf16
    unsigned short* e1t = (unsigned short*)(mo + (size_t)BT * 64 / 2); // (b,T,128) bf16
    unsigned short* comb_bf = (unsigned short*)xn_buf;   // overlay after xn dead
    unsigned short* d_bf = (unsigned short*)mo;          // overlay after mo dead

    // single mega prep dispatch: weights + bnfold + casts + combos + transpose
    k_prep<<<7009, 256, 0, stream>>>(enc_w1, enc_w2, convd_w, sp_w,
                                     convd_b, bn_g, bn_b, bn_mean, bn_var,
                                     inW0, inW1, outW0, outW1, xW0, xW1, dtW0, dtW1,
                                     x, W1r, W2r, Wdr, Wspr, alpha_d, beta_d,
                                     inW_bf2, outW_bf2, xW_bc2, Wcombo2, xt);

    // encoder
    k_conv3_bf<<<dim3(BT / 128, 1), 256, 0, stream>>>(xt, 64, nullptr, 0, W1r,
                                                      nullptr, enc_b1, nullptr, e1t, 128, 1, 0);
    k_conv3_bf<<<dim3(BT / 128, 2), 256, 0, stream>>>(e1t, 128, nullptr, 0, W2r,
                                                      nullptr, enc_b2, t_buf, tb_bf, 256, 1, 0);
    k_rmsnorm<<<BT / 4, 256, 0, stream>>>(t_buf, norm1_w, xn_buf, xn_bf, BT);

    for (int dir = 0; dir < 2; dir++) {
        const float* convW = (const float*)d_in[8 + 9 * dir];
        const float* convb = (const float*)d_in[9 + 9 * dir];
        const float* dtb   = (const float*)d_in[12 + 9 * dir];
        const float* Alog  = (const float*)d_in[13 + 9 * dir];
        const float* Dp    = (const float*)d_in[14 + 9 * dir];
        const unsigned short* inW_d  = inW_bf2 + (size_t)dir * 1024 * DM;
        const unsigned short* outW_d = outW_bf2 + (size_t)dir * DM * DI;
        const unsigned short* Wc_d   = Wcombo2 + (size_t)dir * DI * DI;
        const unsigned short* xWbc_d = xW_bc2 + (size_t)dir * 32 * DI;
        int rev = dir;
        for (int b0 = 0; b0 < B_SZ; b0 += Bc) {
            int Tc = Bc * T_LR;
            unsigned short* xcs = (unsigned short*)scratch;                       // bf16, later y
            unsigned short* dtb16 = xcs + (size_t)Tc * DI;                        // bf16, later yg
            float* db   = (float*)(dtb16 + (size_t)Tc * DI);
            float* hS   = db + (size_t)Tc * 32;
            float* csum = hS + (size_t)Bc * CH * DI * DS;
            const float*          xnC  = xn_buf + (size_t)b0 * T_LR * DM;
            const unsigned short* xnbC = xn_bf  + (size_t)b0 * T_LR * DM;
            float*                moC  = mo     + (size_t)b0 * T_LR * DM;
            // fused in_proj(xc) + causal dwconv + silu -> xcs bf16
            k_inproj_conv<<<dim3(Tc / 128, DI / 128), 256, 0, stream>>>(
                xnbC, inW_d, convW, convb, xcs, rev);
            // dt = softplus(xcs @ Wcombo^T + dtb) -> bf16  [vectorized epilogue]
            k_gemm_bf_cb<<<dim3(Tc / 128, DI / 128), 256, 0, stream>>>(
                xcs, DI, Wc_d, dtb16, DI, dtb, nullptr, DI, 2, 0);
            // db (B,C) = xcs @ xW[16:48]^T -> fp32 (Tc,32)
            k_gemm_bf<<<dim3(Tc / 128, 1), 256, 0, stream>>>(
                xcs, DI, xWbc_d, db, nullptr, 32, nullptr, nullptr, nullptr,
                DI, 32, 0, 0, 0, 0);
            // chunked scan (CH=128, CLEN=20); y bf16 in place over xcs
            k_scan_p1<<<(Bc * CH * DI) / 256, 256, 0, stream>>>(dtb16, xcs, db, Alog, hS, csum);
            k_scan_p2<<<(Bc * DI * DS) / 256, 256, 0, stream>>>(hS, csum, Alog);
            k_scan_p3<<<(Bc * CH * DI) / 256, 256, 0, stream>>>(dtb16, xcs, db, Alog, Dp, hS);
            // z GEMM + gate: yg = bf16(silu(z) * y) -> overlays dt buffer  [vectorized epilogue]
            k_gemm_bf_cb<<<dim3(Tc / 128, DI / 128), 256, 0, stream>>>(
                xnbC, DM, inW_d + (size_t)DI * DM, dtb16, DI, nullptr, xcs, DM, 0, rev);
            // mo (+)= yg @ outW^T + xn
            k_gemm_bf<<<dim3(Tc / 128, DM / 128), 256, 0, stream>>>(
                dtb16, DI, outW_d, moC, nullptr, DM, xnC, nullptr, nullptr,
                DI, DM, 0, 0, rev, dir);
        }
    }

    // combined = rmsnorm(mo) -> comb_bf (xn_buf overlay)
    k_rmsnorm<<<BT / 4, 256, 0, stream>>>(mo, norm2_w, nullptr, comb_bf, BT);
    // convd + bn + silu -> d_bf (mo overlay)
    k_conv3_bf<<<dim3(BT / 128, 2), 256, 0, stream>>>(comb_bf, 256, tb_bf, 256, Wdr,
                                                      alpha_d, beta_d, nullptr, d_bf, 256, 1, 0);
    // sp conv + pixel shuffle -> out
    k_conv3_bf<<<dim3(BT / 128, 1), 256, 0, stream>>>(d_bf, 256, nullptr, 0, Wspr,
                                                      nullptr, sp_b, out, nullptr, 128, 0, 1);
}